// Round 5
// baseline (1026.427 us; speedup 1.0000x reference)
//
#include <hip/hip_runtime.h>
#include <hip/hip_bf16.h>
#include <cstdint>

// SemlaLayer fused forward for MI355X (gfx950).
// R4: latency-overlap restructure — reg-staged next tile (T14), batched W/proj
// loads, 4 barriers/tile, separate H buffer, W2 column reorder (edge cols
// first, 64B-aligned direct stores), plain (non-nt) edge stores for WRITE A/B.

typedef __bf16 bf16x4_t __attribute__((ext_vector_type(4)));
typedef __bf16 bf16x8_t __attribute__((ext_vector_type(8)));
typedef float  f32x4_t  __attribute__((ext_vector_type(4)));

#define SP 76   // sS pitch in floats
#define KV 32   // k-tile rows

__device__ __forceinline__ int swz(int row, int col) {
    return (row << 8) + (col ^ ((row & 7) << 3));
}

__device__ __forceinline__ bf16x4_t cvt4(f32x4_t v) {
    bf16x4_t r;
    r[0] = (__bf16)v.x; r[1] = (__bf16)v.y; r[2] = (__bf16)v.z; r[3] = (__bf16)v.w;
    return r;
}

// ---------------- pre-kernel: projections + weight conversion ----------------
// W2bf row layout (reordered): rows 0..63 = edge channels (orig 72..135),
// rows 64..135 = logits (orig 0..71), rows 136..143 = pad.
__global__ __launch_bounds__(256) void semla_pre(
    const float* __restrict__ invs, const float* __restrict__ equis,
    const float* __restrict__ Wq, const float* __restrict__ bq,
    const float* __restrict__ Wk, const float* __restrict__ bk,
    const float* __restrict__ Wc, const float* __restrict__ Wi, const float* __restrict__ bi,
    const float* __restrict__ W1, const float* __restrict__ W2,
    __bf16* __restrict__ W1bf, __bf16* __restrict__ W2bf,
    float* __restrict__ qmsg, float* __restrict__ kmsg,
    float* __restrict__ projE, float* __restrict__ projF)
{
    const int blk = blockIdx.x, tid = threadIdx.x;
    if (blk < 128) {
        const int r0 = blk * 8;
        __shared__ __align__(16) float sInv8[8][256];
        __shared__ __align__(16) float sEqu8[8][192];
        #pragma unroll
        for (int j = 0; j < 8; ++j) {
            sInv8[j][tid] = invs[(size_t)(r0 + j) * 256 + tid];
            if (tid < 192) sEqu8[j][tid] = equis[(size_t)(r0 + j) * 192 + tid];
        }
        __syncthreads();
        {
            float acc[8] = {0.f,0.f,0.f,0.f,0.f,0.f,0.f,0.f};
            const float* w = &Wi[tid * 256];
            for (int i = 0; i < 256; i += 4) {
                f32x4_t ww = *(const f32x4_t*)&w[i];
                #pragma unroll
                for (int j = 0; j < 8; ++j) {
                    const float* x = &sInv8[j][i];
                    acc[j] += ww.x * x[0] + ww.y * x[1] + ww.z * x[2] + ww.w * x[3];
                }
            }
            const float bb = bi[tid];
            #pragma unroll
            for (int j = 0; j < 8; ++j) projF[(size_t)(r0 + j) * 256 + tid] = acc[j] + bb;
        }
        if (tid < 128) {
            const int d = tid & 63;
            const float* w = (tid < 64) ? &Wq[d * 256] : &Wk[d * 256];
            float acc[8] = {0.f,0.f,0.f,0.f,0.f,0.f,0.f,0.f};
            for (int i = 0; i < 256; i += 4) {
                f32x4_t ww = *(const f32x4_t*)&w[i];
                #pragma unroll
                for (int j = 0; j < 8; ++j) {
                    const float* x = &sInv8[j][i];
                    acc[j] += ww.x * x[0] + ww.y * x[1] + ww.z * x[2] + ww.w * x[3];
                }
            }
            const float bb = (tid < 64) ? bq[d] : bk[d];
            float* dst = (tid < 64) ? qmsg : kmsg;
            #pragma unroll
            for (int j = 0; j < 8; ++j) dst[(size_t)(r0 + j) * 64 + d] = acc[j] + bb;
        }
        if (tid < 192) {
            const int c = tid >> 6, e = tid & 63;
            const float* w = &Wc[e * 64];
            float acc[8] = {0.f,0.f,0.f,0.f,0.f,0.f,0.f,0.f};
            for (int dd = 0; dd < 64; dd += 4) {
                f32x4_t ww = *(const f32x4_t*)&w[dd];
                #pragma unroll
                for (int j = 0; j < 8; ++j) {
                    const float* x = &sEqu8[j][c * 64 + dd];
                    acc[j] += ww.x * x[0] + ww.y * x[1] + ww.z * x[2] + ww.w * x[3];
                }
            }
            #pragma unroll
            for (int j = 0; j < 8; ++j) projE[(size_t)(r0 + j) * 192 + tid] = acc[j];
        }
    } else if (blk < 144) {
        const int base = (blk - 128) * 4096;
        #pragma unroll
        for (int r = 0; r < 16; ++r) {
            const int idx = base + r * 256 + tid;
            W1bf[idx] = (__bf16)W1[idx];
        }
    } else if (blk < 153) {
        const int base = (blk - 144) * 4096;
        #pragma unroll
        for (int r = 0; r < 16; ++r) {
            const int idx = base + r * 256 + tid;     // idx < 144*256
            const int o = idx >> 8, cc = idx & 255;
            const int src = (o < 64) ? (72 + o) : (o < 136 ? o - 64 : -1);
            W2bf[idx] = (src >= 0) ? (__bf16)W2[src * 256 + cc] : (__bf16)0.f;
        }
    }
}

// ---------------- main fused kernel: one workgroup per (b,q) ----------------
__global__ __launch_bounds__(256, 3) void semla_main(
    const float* __restrict__ equis, const float* __restrict__ edges,
    const int* __restrict__ adj,
    const __bf16* __restrict__ W1bf, const __bf16* __restrict__ W2bf,
    const float* __restrict__ qmsg, const float* __restrict__ kmsg,
    const float* __restrict__ projE, const float* __restrict__ projF,
    const float* __restrict__ b1, const float* __restrict__ b2,
    const float* __restrict__ Wa, const float* __restrict__ Wo,
    const float* __restrict__ bo,
    float* __restrict__ outE, float* __restrict__ outI, float* __restrict__ outEdge)
{
    const int bqid = ((blockIdx.x & 7) << 7) | (blockIdx.x >> 3);  // XCD swizzle
    const int b = bqid >> 8;
    const int tid = threadIdx.x;
    const int wave = tid >> 6, lane = tid & 63;
    const int arow = lane & 15, kgrp = lane >> 4;

    __shared__ __align__(16) __bf16 sX[KV * 256];   // 16KB X tile
    __shared__ __align__(16) __bf16 sH[KV * 256];   // 16KB H tile
    __shared__ __align__(16) float  sS[KV * SP];    // logits -> p
    __shared__ __align__(16) float  sB1[256];
    __shared__ __align__(16) float  sB2[144];
    __shared__ __align__(16) float  sEquiQ[192];
    __shared__ __align__(16) __bf16 sQm[64];
    __shared__ float sF[72], sL[72], sL2[72];
    __shared__ int   sAdj[2][KV];

    sB1[tid] = b1[tid];
    if (tid < 144) sB2[tid] = (tid < 64) ? b2[72 + tid] : (tid < 136 ? b2[tid - 64] : 0.f);
    if (tid < 192) sEquiQ[tid] = equis[(size_t)bqid * 192 + tid];
    if (tid < 64)  sQm[tid] = (__bf16)qmsg[(size_t)bqid * 64 + tid];

    float m_run = -1e30f, l_run = 0.f, l2_run = 0.f;
    float accE = 0.f;                       // role (c,d) for tid<192
    float accI = 0.f;                       // role (h,dd)
    const int c_e = tid >> 6, d_e = tid & 63;
    const int h_i = tid >> 5;

    const int r0s = tid >> 4, c4s = (tid & 15) << 2;   // staging coords (rows r0s, r0s+16)

    __syncthreads();                          // init visible

    // ---- prologue: stage X[0] ----
    {
        const int kb = b * 256;
        #pragma unroll
        for (int it = 0; it < 2; ++it) {
            const int r = r0s + it * 16;
            f32x4_t km = *(const f32x4_t*)&kmsg[(size_t)(kb + r) * 64 + c4s];
            const float* ek = &equis[(size_t)(kb + r) * 192 + c4s];
            f32x4_t e0 = *(const f32x4_t*)(ek);
            f32x4_t e1 = *(const f32x4_t*)(ek + 64);
            f32x4_t e2 = *(const f32x4_t*)(ek + 128);
            f32x4_t ed = __builtin_nontemporal_load(
                (const f32x4_t*)&edges[((size_t)bqid * 256 + r) * 64 + c4s]);
            f32x4_t q0 = *(const f32x4_t*)&sEquiQ[c4s];
            f32x4_t q1 = *(const f32x4_t*)&sEquiQ[64 + c4s];
            f32x4_t q2 = *(const f32x4_t*)&sEquiQ[128 + c4s];
            *(bf16x4_t*)&sX[swz(r, c4s)]        = *(const bf16x4_t*)&sQm[c4s];
            *(bf16x4_t*)&sX[swz(r, 64 + c4s)]   = cvt4(km);
            *(bf16x4_t*)&sX[swz(r, 128 + c4s)]  = cvt4(e0 * q0 + e1 * q1 + e2 * q2);
            *(bf16x4_t*)&sX[swz(r, 192 + c4s)]  = cvt4(ed);
        }
        if (tid < KV) sAdj[0][tid] = adj[(size_t)bqid * 256 + tid];
    }
    __syncthreads();                          // X[0] ready

    for (int kt = 0; kt < 8; ++kt) {
        const int k0 = kt * KV;
        const int kb = b * 256 + k0;
        const int cur = kt & 1;

        // ---- issue stage loads for tile kt+1 (global -> regs, T14) ----
        f32x4_t km_[2], e0_[2], e1_[2], e2_[2], ed_[2];
        int adjR = 0;
        if (kt < 7) {
            const int kb2 = kb + KV;
            #pragma unroll
            for (int it = 0; it < 2; ++it) {
                const int r = r0s + it * 16;
                km_[it] = *(const f32x4_t*)&kmsg[(size_t)(kb2 + r) * 64 + c4s];
                const float* ek = &equis[(size_t)(kb2 + r) * 192 + c4s];
                e0_[it] = *(const f32x4_t*)(ek);
                e1_[it] = *(const f32x4_t*)(ek + 64);
                e2_[it] = *(const f32x4_t*)(ek + 128);
                ed_[it] = __builtin_nontemporal_load(
                    (const f32x4_t*)&edges[((size_t)bqid * 256 + k0 + KV + r) * 64 + c4s]);
            }
            if (tid < KV) adjR = adj[(size_t)bqid * 256 + k0 + KV + tid];
        }

        // ---- GEMM1: acc1 = X @ W1^T (wave owns 64 FF cols), batched W loads ----
        f32x4_t acc1[2][4];
        {
            const f32x4_t z = {0.f, 0.f, 0.f, 0.f};
            #pragma unroll
            for (int rt = 0; rt < 2; ++rt)
                #pragma unroll
                for (int ct = 0; ct < 4; ++ct) acc1[rt][ct] = z;
        }
        #pragma unroll
        for (int kh = 0; kh < 4; ++kh) {
            bf16x8_t bw[8];
            #pragma unroll
            for (int q = 0; q < 8; ++q) {
                const int ks = kh * 2 + (q >> 2), ct = q & 3;
                bw[q] = *(const bf16x8_t*)
                    &W1bf[(((wave << 6) + (ct << 4) + arow) << 8) + ks * 32 + (kgrp << 3)];
            }
            #pragma unroll
            for (int k2 = 0; k2 < 2; ++k2) {
                const int kk = (kh * 2 + k2) * 32 + (kgrp << 3);
                bf16x8_t a0 = *(const bf16x8_t*)&sX[swz(arow, kk)];
                bf16x8_t a1 = *(const bf16x8_t*)&sX[swz(16 + arow, kk)];
                #pragma unroll
                for (int ct = 0; ct < 4; ++ct) {
                    acc1[0][ct] = __builtin_amdgcn_mfma_f32_16x16x32_bf16(a0, bw[k2*4+ct], acc1[0][ct], 0, 0, 0);
                    acc1[1][ct] = __builtin_amdgcn_mfma_f32_16x16x32_bf16(a1, bw[k2*4+ct], acc1[1][ct], 0, 0, 0);
                }
            }
        }
        __syncthreads();                      // (A) all waves done reading sX

        // ---- write X[kt+1] from staged regs ----
        if (kt < 7) {
            f32x4_t q0 = *(const f32x4_t*)&sEquiQ[c4s];
            f32x4_t q1 = *(const f32x4_t*)&sEquiQ[64 + c4s];
            f32x4_t q2 = *(const f32x4_t*)&sEquiQ[128 + c4s];
            #pragma unroll
            for (int it = 0; it < 2; ++it) {
                const int r = r0s + it * 16;
                *(bf16x4_t*)&sX[swz(r, c4s)]       = *(const bf16x4_t*)&sQm[c4s];
                *(bf16x4_t*)&sX[swz(r, 64 + c4s)]  = cvt4(km_[it]);
                *(bf16x4_t*)&sX[swz(r, 128 + c4s)] = cvt4(e0_[it]*q0 + e1_[it]*q1 + e2_[it]*q2);
                *(bf16x4_t*)&sX[swz(r, 192 + c4s)] = cvt4(ed_[it]);
            }
            if (tid < KV) sAdj[cur ^ 1][tid] = adjR;
        }

        // ---- GEMM1 epilogue: silu -> sH ----
        #pragma unroll
        for (int rt = 0; rt < 2; ++rt)
            #pragma unroll
            for (int ct = 0; ct < 4; ++ct) {
                const int ccol = (wave << 6) + (ct << 4) + arow;
                const float bb = sB1[ccol];
                #pragma unroll
                for (int j = 0; j < 4; ++j) {
                    const int row = (rt << 4) + (kgrp << 2) + j;
                    float x = acc1[rt][ct][j] + bb;
                    float hh = x * (1.0f / (1.0f + __expf(-x)));
                    sH[swz(row, ccol)] = (__bf16)hh;
                }
            }
        __syncthreads();                      // (B) sH (and sX[kt+1]) ready

        // ---- GEMM2: messages = H @ W2bf^T, 9 col-tiles over 4 waves ----
        const int ct0 = (wave < 2) ? wave * 2 : (wave == 2 ? 4 : 7);
        const int nct = (wave == 2) ? 3 : 2;
        f32x4_t acc2[2][3];
        {
            const f32x4_t z = {0.f, 0.f, 0.f, 0.f};
            #pragma unroll
            for (int rt = 0; rt < 2; ++rt)
                #pragma unroll
                for (int ci = 0; ci < 3; ++ci) acc2[rt][ci] = z;
        }
        #pragma unroll
        for (int kh = 0; kh < 4; ++kh) {
            bf16x8_t bw[2][3];
            #pragma unroll
            for (int k2 = 0; k2 < 2; ++k2)
                #pragma unroll
                for (int ci = 0; ci < 3; ++ci)
                    if (ci < nct) {
                        const int ks = kh * 2 + k2;
                        bw[k2][ci] = *(const bf16x8_t*)
                            &W2bf[(((ct0 + ci) << 4) + arow) * 256 + ks * 32 + (kgrp << 3)];
                    }
            #pragma unroll
            for (int k2 = 0; k2 < 2; ++k2) {
                const int kk = (kh * 2 + k2) * 32 + (kgrp << 3);
                bf16x8_t a0 = *(const bf16x8_t*)&sH[swz(arow, kk)];
                bf16x8_t a1 = *(const bf16x8_t*)&sH[swz(16 + arow, kk)];
                #pragma unroll
                for (int ci = 0; ci < 3; ++ci)
                    if (ci < nct) {
                        acc2[0][ci] = __builtin_amdgcn_mfma_f32_16x16x32_bf16(a0, bw[k2][ci], acc2[0][ci], 0, 0, 0);
                        acc2[1][ci] = __builtin_amdgcn_mfma_f32_16x16x32_bf16(a1, bw[k2][ci], acc2[1][ci], 0, 0, 0);
                    }
            }
        }

        // ---- epilogue: edge cols (0..63) -> global direct, logits -> sS ----
        #pragma unroll
        for (int ci = 0; ci < 3; ++ci)
            if (ci < nct) {
                const int col = ((ct0 + ci) << 4) + arow;
                const float bb = sB2[col];
                #pragma unroll
                for (int rt = 0; rt < 2; ++rt)
                    #pragma unroll
                    for (int j = 0; j < 4; ++j) {
                        const int r = (rt << 4) + (kgrp << 2) + j;
                        const float v = acc2[rt][ci][j] + bb;
                        if (col < 64)
                            outEdge[((size_t)bqid * 256 + k0 + r) * 64 + col] = v;
                        else if (col < 136)
                            sS[r * SP + (col - 64)] = v;
                    }
            }
        __syncthreads();                      // (C) logits ready

        // ---- pass A: per-channel online softmax ----
        if (tid < 72) {
            float tm = -1e30f;
            #pragma unroll 8
            for (int k = 0; k < KV; ++k)
                if (sAdj[cur][k]) tm = fmaxf(tm, sS[k * SP + tid]);
            const float mN = fmaxf(m_run, tm);
            const float f = __expf(m_run - mN);
            float s1 = 0.f, s2 = 0.f;
            #pragma unroll 8
            for (int k = 0; k < KV; ++k) {
                float p = sAdj[cur][k] ? __expf(sS[k * SP + tid] - mN) : 0.f;
                sS[k * SP + tid] = p;
                s1 += p; s2 += p * p;
            }
            l_run = l_run * f + s1;
            l2_run = l2_run * f * f + s2;
            m_run = mN;
            sF[tid] = f;
        }
        __syncthreads();                      // (D) p + rescale ready

        // ---- pass B: accumulate attention outputs (batched prefetch) ----
        if (tid < 192) {
            float a = accE * sF[d_e];
            const float* pe = &projE[((size_t)kb * 3 + c_e) * 64 + d_e];
            #pragma unroll
            for (int h = 0; h < 2; ++h) {
                float pr[16];
                #pragma unroll
                for (int t = 0; t < 16; ++t) pr[t] = pe[(h * 16 + t) * 192];
                #pragma unroll
                for (int t = 0; t < 16; ++t) a += sS[(h * 16 + t) * SP + d_e] * pr[t];
            }
            accE = a;
        }
        {
            float a = accI * sF[64 + h_i];
            const float* pf = &projF[(size_t)kb * 256 + tid];
            #pragma unroll
            for (int h = 0; h < 2; ++h) {
                float pr[16];
                #pragma unroll
                for (int t = 0; t < 16; ++t) pr[t] = pf[(h * 16 + t) * 256];
                #pragma unroll
                for (int t = 0; t < 16; ++t) a += sS[(h * 16 + t) * SP + 64 + h_i] * pr[t];
            }
            accI = a;
        }
        // next writes to sS/sF occur only after barriers A,B of tile kt+1
    }

    // ---- finalize ----
    if (tid < 72) { sL[tid] = l_run; sL2[tid] = l2_run; }
    __syncthreads();
    if (tid < 192) {
        const float ll = sL[d_e];
        sS[tid] = accE * sqrtf(sL2[d_e]) / (ll * ll);            // out_e[c][d]
    }
    {
        const float ll = sL[64 + h_i];
        sS[256 + tid] = accI * sqrtf(sL2[64 + h_i]) / (ll * ll); // out_i flat
    }
    __syncthreads();
    if (tid < 192) {                          // equi_updates = out_e @ Wa^T
        const int c = tid >> 6, e = tid & 63;
        float s = 0.f;
        #pragma unroll 8
        for (int d2 = 0; d2 < 64; ++d2) s += sS[c * 64 + d2] * Wa[e * 64 + d2];
        outE[((size_t)bqid * 3 + c) * 64 + e] = s;
    }
    {                                         // inv_updates = out_i @ Wo^T + bo
        float s = 0.f;
        const float* wo = &Wo[tid * 256];
        #pragma unroll 8
        for (int i = 0; i < 256; ++i) s += sS[256 + i] * wo[i];
        outI[(size_t)bqid * 256 + tid] = s + bo[tid];
    }
}

extern "C" void kernel_launch(void* const* d_in, const int* in_sizes, int n_in,
                              void* d_out, int out_size, void* d_ws, size_t ws_size,
                              hipStream_t stream) {
    (void)in_sizes; (void)n_in; (void)out_size; (void)ws_size;
    const float* equis = (const float*)d_in[0];
    const float* invs  = (const float*)d_in[1];
    const float* edges = (const float*)d_in[2];
    const int*   adj   = (const int*)d_in[3];
    const float* Wq = (const float*)d_in[4];
    const float* bq = (const float*)d_in[5];
    const float* Wk = (const float*)d_in[6];
    const float* bk = (const float*)d_in[7];
    const float* W1 = (const float*)d_in[8];
    const float* b1 = (const float*)d_in[9];
    const float* W2 = (const float*)d_in[10];
    const float* b2 = (const float*)d_in[11];
    const float* Wc = (const float*)d_in[12];
    const float* Wa = (const float*)d_in[13];
    const float* Wi = (const float*)d_in[14];
    const float* bi = (const float*)d_in[15];
    const float* Wo = (const float*)d_in[16];
    const float* bo = (const float*)d_in[17];

    float* out = (float*)d_out;
    float* outE    = out;                  // (B,N,3,64)  = 196608
    float* outI    = out + 196608;         // (B,N,256)   = 262144
    float* outEdge = out + 458752;         // (B,N,N,64)  = 16777216

    char* ws = (char*)d_ws;
    __bf16* W1bf = (__bf16*)(ws);                    // 131072 B
    __bf16* W2bf = (__bf16*)(ws + 131072);           //  73728 B
    float* qmsg  = (float*)(ws + 204800);            // 262144 B
    float* kmsg  = (float*)(ws + 466944);            // 262144 B
    float* projE = (float*)(ws + 729088);            // 786432 B
    float* projF = (float*)(ws + 1515520);           // 1048576 B

    semla_pre<<<153, 256, 0, stream>>>(invs, equis, Wq, bq, Wk, bk, Wc, Wi, bi,
                                       W1, W2, W1bf, W2bf, qmsg, kmsg, projE, projF);
    semla_main<<<1024, 256, 0, stream>>>(equis, edges, adj, W1bf, W2bf, qmsg, kmsg,
                                         projE, projF, b1, b2, Wa, Wo, bo,
                                         outE, outI, outEdge);
}

// Round 6
// 743.038 us; speedup vs baseline: 1.3814x; 1.3814x over previous
//
#include <hip/hip_runtime.h>
#include <hip/hip_bf16.h>
#include <cstdint>

// SemlaLayer fused forward for MI355X (gfx950).
// R6: occupancy play — 512-thread blocks (8 waves), work split 8-way per phase,
// LDS ~29KB (in-place X/H, direct W2-reordered edge stores), no nt hints,
// no XCD swizzle. Target 32 waves/CU.

typedef __bf16 bf16x4_t __attribute__((ext_vector_type(4)));
typedef __bf16 bf16x8_t __attribute__((ext_vector_type(8)));
typedef float  f32x4_t  __attribute__((ext_vector_type(4)));

#define SP 76   // sS pitch in floats
#define KV 32   // k-tile rows

__device__ __forceinline__ int swz(int row, int col) {
    // element-index XOR swizzle at 8-element (16B) granularity (G4).
    return (row << 8) + (col ^ ((row & 7) << 3));
}

__device__ __forceinline__ bf16x4_t cvt4(f32x4_t v) {
    bf16x4_t r;
    r[0] = (__bf16)v.x; r[1] = (__bf16)v.y; r[2] = (__bf16)v.z; r[3] = (__bf16)v.w;
    return r;
}

// ---------------- pre-kernel: projections + weight conversion ----------------
// W2bf row layout (reordered): rows 0..63 = edge channels (orig 72..135),
// rows 64..135 = logits (orig 0..71), rows 136..143 = pad.
__global__ __launch_bounds__(256) void semla_pre(
    const float* __restrict__ invs, const float* __restrict__ equis,
    const float* __restrict__ Wq, const float* __restrict__ bq,
    const float* __restrict__ Wk, const float* __restrict__ bk,
    const float* __restrict__ Wc, const float* __restrict__ Wi, const float* __restrict__ bi,
    const float* __restrict__ W1, const float* __restrict__ W2,
    __bf16* __restrict__ W1bf, __bf16* __restrict__ W2bf,
    float* __restrict__ qmsg, float* __restrict__ kmsg,
    float* __restrict__ projE, float* __restrict__ projF)
{
    const int blk = blockIdx.x, tid = threadIdx.x;
    if (blk < 128) {
        const int r0 = blk * 8;
        __shared__ __align__(16) float sInv8[8][256];
        __shared__ __align__(16) float sEqu8[8][192];
        #pragma unroll
        for (int j = 0; j < 8; ++j) {
            sInv8[j][tid] = invs[(size_t)(r0 + j) * 256 + tid];
            if (tid < 192) sEqu8[j][tid] = equis[(size_t)(r0 + j) * 192 + tid];
        }
        __syncthreads();
        {
            float acc[8] = {0.f,0.f,0.f,0.f,0.f,0.f,0.f,0.f};
            const float* w = &Wi[tid * 256];
            for (int i = 0; i < 256; i += 4) {
                f32x4_t ww = *(const f32x4_t*)&w[i];
                #pragma unroll
                for (int j = 0; j < 8; ++j) {
                    const float* x = &sInv8[j][i];
                    acc[j] += ww.x * x[0] + ww.y * x[1] + ww.z * x[2] + ww.w * x[3];
                }
            }
            const float bb = bi[tid];
            #pragma unroll
            for (int j = 0; j < 8; ++j) projF[(size_t)(r0 + j) * 256 + tid] = acc[j] + bb;
        }
        if (tid < 128) {
            const int d = tid & 63;
            const float* w = (tid < 64) ? &Wq[d * 256] : &Wk[d * 256];
            float acc[8] = {0.f,0.f,0.f,0.f,0.f,0.f,0.f,0.f};
            for (int i = 0; i < 256; i += 4) {
                f32x4_t ww = *(const f32x4_t*)&w[i];
                #pragma unroll
                for (int j = 0; j < 8; ++j) {
                    const float* x = &sInv8[j][i];
                    acc[j] += ww.x * x[0] + ww.y * x[1] + ww.z * x[2] + ww.w * x[3];
                }
            }
            const float bb = (tid < 64) ? bq[d] : bk[d];
            float* dst = (tid < 64) ? qmsg : kmsg;
            #pragma unroll
            for (int j = 0; j < 8; ++j) dst[(size_t)(r0 + j) * 64 + d] = acc[j] + bb;
        }
        if (tid < 192) {
            const int c = tid >> 6, e = tid & 63;
            const float* w = &Wc[e * 64];
            float acc[8] = {0.f,0.f,0.f,0.f,0.f,0.f,0.f,0.f};
            for (int dd = 0; dd < 64; dd += 4) {
                f32x4_t ww = *(const f32x4_t*)&w[dd];
                #pragma unroll
                for (int j = 0; j < 8; ++j) {
                    const float* x = &sEqu8[j][c * 64 + dd];
                    acc[j] += ww.x * x[0] + ww.y * x[1] + ww.z * x[2] + ww.w * x[3];
                }
            }
            #pragma unroll
            for (int j = 0; j < 8; ++j) projE[(size_t)(r0 + j) * 192 + tid] = acc[j];
        }
    } else if (blk < 144) {
        const int base = (blk - 128) * 4096;
        #pragma unroll
        for (int r = 0; r < 16; ++r) {
            const int idx = base + r * 256 + tid;
            W1bf[idx] = (__bf16)W1[idx];
        }
    } else if (blk < 153) {
        const int base = (blk - 144) * 4096;
        #pragma unroll
        for (int r = 0; r < 16; ++r) {
            const int idx = base + r * 256 + tid;     // idx < 144*256
            const int o = idx >> 8, cc = idx & 255;
            const int src = (o < 64) ? (72 + o) : (o < 136 ? o - 64 : -1);
            W2bf[idx] = (src >= 0) ? (__bf16)W2[src * 256 + cc] : (__bf16)0.f;
        }
    }
}

// ---------------- main fused kernel: one 8-wave workgroup per (b,q) ----------
__global__ __launch_bounds__(512, 8) void semla_main(
    const float* __restrict__ equis, const float* __restrict__ edges,
    const int* __restrict__ adj,
    const __bf16* __restrict__ W1bf, const __bf16* __restrict__ W2bf,
    const float* __restrict__ qmsg, const float* __restrict__ kmsg,
    const float* __restrict__ projE, const float* __restrict__ projF,
    const float* __restrict__ b1, const float* __restrict__ b2,
    const float* __restrict__ Wa, const float* __restrict__ Wo,
    const float* __restrict__ bo,
    float* __restrict__ outE, float* __restrict__ outI, float* __restrict__ outEdge)
{
    const int bqid = blockIdx.x;          // b*256 + q
    const int b = bqid >> 8;
    const int tid = threadIdx.x;
    const int wave = tid >> 6, lane = tid & 63;
    const int arow = lane & 15, kgrp = lane >> 4;

    __shared__ __align__(16) __bf16 sX[KV * 256];   // 16KB: X tile, then H in place
    __shared__ __align__(16) float  sS[KV * SP];    // logits -> p
    __shared__ __align__(16) float  sB1[256];
    __shared__ __align__(16) float  sB2[144];
    __shared__ __align__(16) float  sEquiQ[192];
    __shared__ __align__(16) __bf16 sQm[64];
    __shared__ float sF[72], sL[72], sL2[72];
    __shared__ int   sAdj[KV];

    if (tid < 256) sB1[tid] = b1[tid];
    if (tid < 144) sB2[tid] = (tid < 64) ? b2[72 + tid] : (tid < 136 ? b2[tid - 64] : 0.f);
    if (tid < 192) sEquiQ[tid] = equis[(size_t)bqid * 192 + tid];
    if (tid < 64)  sQm[tid] = (__bf16)qmsg[(size_t)bqid * 64 + tid];

    // persistent per-thread attention state
    float m_run = -1e30f, l_run = 0.f, l2_run = 0.f;
    float accE = 0.f;                       // role (c,d) for tid<192
    float accI = 0.f;                       // role fidx = tid-256 for tid>=256
    const int c_e = tid >> 6, d_e = tid & 63;
    const int fidx = tid & 255;             // for tid>=256: h=fidx>>5
    const int h_i = fidx >> 5;

    const int r0s = tid >> 4, c4s = (tid & 15) << 2;  // staging: row r0s (0..31)
    __syncthreads();                        // init LDS visible

    for (int kt = 0; kt < 8; ++kt) {
        const int k0 = kt * KV;
        const int kb = b * 256 + k0;

        // ---- build X tile [32 rows][qmsg|kmsg|dot|edges] bf16, one pass ----
        {
            const int r = r0s;
            f32x4_t km = *(const f32x4_t*)&kmsg[(size_t)(kb + r) * 64 + c4s];
            const float* ek = &equis[(size_t)(kb + r) * 192 + c4s];
            f32x4_t e0 = *(const f32x4_t*)(ek);
            f32x4_t e1 = *(const f32x4_t*)(ek + 64);
            f32x4_t e2 = *(const f32x4_t*)(ek + 128);
            f32x4_t ed = *(const f32x4_t*)&edges[((size_t)bqid * 256 + k0 + r) * 64 + c4s];
            f32x4_t q0 = *(const f32x4_t*)&sEquiQ[c4s];
            f32x4_t q1 = *(const f32x4_t*)&sEquiQ[64 + c4s];
            f32x4_t q2 = *(const f32x4_t*)&sEquiQ[128 + c4s];
            *(bf16x4_t*)&sX[swz(r, c4s)]       = *(const bf16x4_t*)&sQm[c4s];
            *(bf16x4_t*)&sX[swz(r, 64 + c4s)]  = cvt4(km);
            *(bf16x4_t*)&sX[swz(r, 128 + c4s)] = cvt4(e0 * q0 + e1 * q1 + e2 * q2);
            *(bf16x4_t*)&sX[swz(r, 192 + c4s)] = cvt4(ed);
        }
        if (tid < KV) sAdj[tid] = adj[(size_t)bqid * 256 + k0 + tid];
        __syncthreads();                      // (1) X staged

        // ---- GEMM1: wave owns 32 FF cols [32w, 32w+32) ----
        f32x4_t acc1[2][2];
        {
            const f32x4_t z = {0.f, 0.f, 0.f, 0.f};
            acc1[0][0] = z; acc1[0][1] = z; acc1[1][0] = z; acc1[1][1] = z;
        }
        #pragma unroll
        for (int ks = 0; ks < 8; ++ks) {
            const int kk = ks * 32 + (kgrp << 3);
            bf16x8_t a0 = *(const bf16x8_t*)&sX[swz(arow, kk)];
            bf16x8_t a1 = *(const bf16x8_t*)&sX[swz(16 + arow, kk)];
            bf16x8_t bw0 = *(const bf16x8_t*)&W1bf[(((wave << 5) + arow) << 8) + kk];
            bf16x8_t bw1 = *(const bf16x8_t*)&W1bf[(((wave << 5) + 16 + arow) << 8) + kk];
            acc1[0][0] = __builtin_amdgcn_mfma_f32_16x16x32_bf16(a0, bw0, acc1[0][0], 0, 0, 0);
            acc1[0][1] = __builtin_amdgcn_mfma_f32_16x16x32_bf16(a0, bw1, acc1[0][1], 0, 0, 0);
            acc1[1][0] = __builtin_amdgcn_mfma_f32_16x16x32_bf16(a1, bw0, acc1[1][0], 0, 0, 0);
            acc1[1][1] = __builtin_amdgcn_mfma_f32_16x16x32_bf16(a1, bw1, acc1[1][1], 0, 0, 0);
        }
        __syncthreads();                      // (2) all waves done reading X

        // ---- silu -> H (in place over X) ----
        #pragma unroll
        for (int rt = 0; rt < 2; ++rt)
            #pragma unroll
            for (int ct = 0; ct < 2; ++ct) {
                const int ccol = (wave << 5) + (ct << 4) + arow;
                const float bb = sB1[ccol];
                #pragma unroll
                for (int j = 0; j < 4; ++j) {
                    const int row = (rt << 4) + (kgrp << 2) + j;
                    float x = acc1[rt][ct][j] + bb;
                    float hh = x * (1.0f / (1.0f + __expf(-x)));
                    sX[swz(row, ccol)] = (__bf16)hh;
                }
            }
        __syncthreads();                      // (3) H ready

        // ---- GEMM2: 9 col-tiles of 16; wave w -> tile w, wave 7 also tile 8 ----
        f32x4_t acc2[2][2];
        {
            const f32x4_t z = {0.f, 0.f, 0.f, 0.f};
            acc2[0][0] = z; acc2[0][1] = z; acc2[1][0] = z; acc2[1][1] = z;
        }
        #pragma unroll
        for (int ks = 0; ks < 8; ++ks) {
            const int kk = ks * 32 + (kgrp << 3);
            bf16x8_t a0 = *(const bf16x8_t*)&sX[swz(arow, kk)];
            bf16x8_t a1 = *(const bf16x8_t*)&sX[swz(16 + arow, kk)];
            bf16x8_t bw0 = *(const bf16x8_t*)&W2bf[(((wave << 4) + arow) << 8) + kk];
            acc2[0][0] = __builtin_amdgcn_mfma_f32_16x16x32_bf16(a0, bw0, acc2[0][0], 0, 0, 0);
            acc2[1][0] = __builtin_amdgcn_mfma_f32_16x16x32_bf16(a1, bw0, acc2[1][0], 0, 0, 0);
            if (wave == 7) {
                bf16x8_t bw1 = *(const bf16x8_t*)&W2bf[((128 + arow) << 8) + kk];
                acc2[0][1] = __builtin_amdgcn_mfma_f32_16x16x32_bf16(a0, bw1, acc2[0][1], 0, 0, 0);
                acc2[1][1] = __builtin_amdgcn_mfma_f32_16x16x32_bf16(a1, bw1, acc2[1][1], 0, 0, 0);
            }
        }
        // epilogue: cols<64 = edge channels -> global; cols 64..135 -> sS logits
        {
            const int col = (wave << 4) + arow;
            const float bb = sB2[col];
            #pragma unroll
            for (int rt = 0; rt < 2; ++rt)
                #pragma unroll
                for (int j = 0; j < 4; ++j) {
                    const int r = (rt << 4) + (kgrp << 2) + j;
                    const float v = acc2[rt][0][j] + bb;
                    if (col < 64)
                        outEdge[((size_t)bqid * 256 + k0 + r) * 64 + col] = v;
                    else
                        sS[r * SP + (col - 64)] = v;
                }
            if (wave == 7) {
                const int col1 = 128 + arow;       // logits ch 64..71 (+pad)
                const float bb1 = sB2[col1];
                if (arow < 8) {
                    #pragma unroll
                    for (int rt = 0; rt < 2; ++rt)
                        #pragma unroll
                        for (int j = 0; j < 4; ++j) {
                            const int r = (rt << 4) + (kgrp << 2) + j;
                            sS[r * SP + (col1 - 64)] = acc2[rt][1][j] + bb1;
                        }
                }
            }
        }
        __syncthreads();                      // (4) logits + adj ready

        // ---- pass A: per-channel online softmax ----
        if (tid < 72) {
            float tm = -1e30f;
            #pragma unroll 8
            for (int k = 0; k < KV; ++k)
                if (sAdj[k]) tm = fmaxf(tm, sS[k * SP + tid]);
            const float mN = fmaxf(m_run, tm);
            const float f = __expf(m_run - mN);
            float s1 = 0.f, s2 = 0.f;
            #pragma unroll 8
            for (int k = 0; k < KV; ++k) {
                float p = sAdj[k] ? __expf(sS[k * SP + tid] - mN) : 0.f;
                sS[k * SP + tid] = p;
                s1 += p; s2 += p * p;
            }
            l_run = l_run * f + s1;
            l2_run = l2_run * f * f + s2;
            m_run = mN;
            sF[tid] = f;
        }
        __syncthreads();                      // (5) p + rescale ready

        // ---- pass B: attention accumulation (waves 0-2: E, waves 4-7: I) ----
        if (tid < 192) {
            float a = accE * sF[d_e];
            const float* pe = &projE[((size_t)kb * 3 + c_e) * 64 + d_e];
            #pragma unroll
            for (int h = 0; h < 2; ++h) {
                float pr[16];
                #pragma unroll
                for (int t = 0; t < 16; ++t) pr[t] = pe[(h * 16 + t) * 192];
                #pragma unroll
                for (int t = 0; t < 16; ++t) a += sS[(h * 16 + t) * SP + d_e] * pr[t];
            }
            accE = a;
        }
        if (tid >= 256) {
            float a = accI * sF[64 + h_i];
            const float* pf = &projF[(size_t)kb * 256 + fidx];
            #pragma unroll
            for (int h = 0; h < 2; ++h) {
                float pr[16];
                #pragma unroll
                for (int t = 0; t < 16; ++t) pr[t] = pf[(h * 16 + t) * 256];
                #pragma unroll
                for (int t = 0; t < 16; ++t) a += sS[(h * 16 + t) * SP + 64 + h_i] * pr[t];
            }
            accI = a;
        }
        // next sS/sF writes happen only after >=2 barriers of tile kt+1
    }

    // ---- finalize ----
    if (tid < 72) { sL[tid] = l_run; sL2[tid] = l2_run; }
    __syncthreads();                          // fences last pass-B sS reads
    if (tid < 192) {
        const float ll = sL[d_e];
        sS[tid] = accE * sqrtf(sL2[d_e]) / (ll * ll);                 // out_e[c][d]
    }
    if (tid >= 256) {
        const float ll = sL[64 + h_i];
        sS[256 + fidx] = accI * sqrtf(sL2[64 + h_i]) / (ll * ll);     // out_i flat
    }
    __syncthreads();
    if (tid < 192) {                          // equi_updates = out_e @ Wa^T
        const int c = tid >> 6, e = tid & 63;
        float s = 0.f;
        #pragma unroll 8
        for (int d2 = 0; d2 < 64; ++d2) s += sS[c * 64 + d2] * Wa[e * 64 + d2];
        outE[((size_t)bqid * 3 + c) * 64 + e] = s;
    }
    if (tid < 256) {                          // inv_updates = out_i @ Wo^T + bo
        float s = 0.f;
        const float* wo = &Wo[tid * 256];
        #pragma unroll 8
        for (int i = 0; i < 256; ++i) s += sS[256 + i] * wo[i];
        outI[(size_t)bqid * 256 + tid] = s + bo[tid];
    }
}

extern "C" void kernel_launch(void* const* d_in, const int* in_sizes, int n_in,
                              void* d_out, int out_size, void* d_ws, size_t ws_size,
                              hipStream_t stream) {
    (void)in_sizes; (void)n_in; (void)out_size; (void)ws_size;
    const float* equis = (const float*)d_in[0];
    const float* invs  = (const float*)d_in[1];
    const float* edges = (const float*)d_in[2];
    const int*   adj   = (const int*)d_in[3];
    const float* Wq = (const float*)d_in[4];
    const float* bq = (const float*)d_in[5];
    const float* Wk = (const float*)d_in[6];
    const float* bk = (const float*)d_in[7];
    const float* W1 = (const float*)d_in[8];
    const float* b1 = (const float*)d_in[9];
    const float* W2 = (const float*)d_in[10];
    const float* b2 = (const float*)d_in[11];
    const float* Wc = (const float*)d_in[12];
    const float* Wa = (const float*)d_in[13];
    const float* Wi = (const float*)d_in[14];
    const float* bi = (const float*)d_in[15];
    const float* Wo = (const float*)d_in[16];
    const float* bo = (const float*)d_in[17];

    float* out = (float*)d_out;
    float* outE    = out;                  // (B,N,3,64)  = 196608
    float* outI    = out + 196608;         // (B,N,256)   = 262144
    float* outEdge = out + 458752;         // (B,N,N,64)  = 16777216

    char* ws = (char*)d_ws;
    __bf16* W1bf = (__bf16*)(ws);                    // 131072 B
    __bf16* W2bf = (__bf16*)(ws + 131072);           //  73728 B
    float* qmsg  = (float*)(ws + 204800);            // 262144 B
    float* kmsg  = (float*)(ws + 466944);            // 262144 B
    float* projE = (float*)(ws + 729088);            // 786432 B
    float* projF = (float*)(ws + 1515520);           // 1048576 B

    semla_pre<<<153, 256, 0, stream>>>(invs, equis, Wq, bq, Wk, bk, Wc, Wi, bi,
                                       W1, W2, W1bf, W2bf, qmsg, kmsg, projE, projF);
    semla_main<<<1024, 512, 0, stream>>>(equis, edges, adj, W1bf, W2bf, qmsg, kmsg,
                                         projE, projF, b1, b2, Wa, Wo, bo,
                                         outE, outI, outEdge);
}

// Round 7
// 617.397 us; speedup vs baseline: 1.6625x; 1.2035x over previous
//
#include <hip/hip_runtime.h>
#include <hip/hip_bf16.h>
#include <cstdint>

// SemlaLayer fused forward for MI355X (gfx950).
// R7: weights register-resident. 1024-thread (16-wave) main blocks; W1 (16
// cols/wave, 32 VGPR) + W2 (16 cols on waves 7-15, 32 VGPR) hoisted before the
// k-loop -> GEMM phases have zero global loads. Final Wa/Wo GEMVs moved to a
// 32-block post-kernel (LDS-staged, in-place over outE/outI regions).

typedef __bf16 bf16x8_t __attribute__((ext_vector_type(8)));
typedef float  f32x4_t  __attribute__((ext_vector_type(4)));

#define SP 76   // sS pitch in floats
#define KV 32   // k-tile rows

__device__ __forceinline__ int swz(int row, int col) {
    // element-index XOR swizzle at 8-element (16B) granularity (G4).
    return (row << 8) + (col ^ ((row & 7) << 3));
}

__device__ __forceinline__ bf16x8_t cvt8(f32x4_t a, f32x4_t b) {
    bf16x8_t r;
    r[0] = (__bf16)a.x; r[1] = (__bf16)a.y; r[2] = (__bf16)a.z; r[3] = (__bf16)a.w;
    r[4] = (__bf16)b.x; r[5] = (__bf16)b.y; r[6] = (__bf16)b.z; r[7] = (__bf16)b.w;
    return r;
}

// ---------------- pre-kernel: projections + weight conversion ----------------
// W2bf row layout (reordered): rows 0..63 = edge channels (orig 72..135),
// rows 64..135 = logits (orig 0..71), rows 136..143 = pad.
__global__ __launch_bounds__(256) void semla_pre(
    const float* __restrict__ invs, const float* __restrict__ equis,
    const float* __restrict__ Wq, const float* __restrict__ bq,
    const float* __restrict__ Wk, const float* __restrict__ bk,
    const float* __restrict__ Wc, const float* __restrict__ Wi, const float* __restrict__ bi,
    const float* __restrict__ W1, const float* __restrict__ W2,
    __bf16* __restrict__ W1bf, __bf16* __restrict__ W2bf,
    float* __restrict__ qmsg, float* __restrict__ kmsg,
    float* __restrict__ projE, float* __restrict__ projF)
{
    const int blk = blockIdx.x, tid = threadIdx.x;
    if (blk < 128) {
        const int r0 = blk * 8;
        __shared__ __align__(16) float sInv8[8][256];
        __shared__ __align__(16) float sEqu8[8][192];
        #pragma unroll
        for (int j = 0; j < 8; ++j) {
            sInv8[j][tid] = invs[(size_t)(r0 + j) * 256 + tid];
            if (tid < 192) sEqu8[j][tid] = equis[(size_t)(r0 + j) * 192 + tid];
        }
        __syncthreads();
        {
            float acc[8] = {0.f,0.f,0.f,0.f,0.f,0.f,0.f,0.f};
            const float* w = &Wi[tid * 256];
            for (int i = 0; i < 256; i += 4) {
                f32x4_t ww = *(const f32x4_t*)&w[i];
                #pragma unroll
                for (int j = 0; j < 8; ++j) {
                    const float* x = &sInv8[j][i];
                    acc[j] += ww.x * x[0] + ww.y * x[1] + ww.z * x[2] + ww.w * x[3];
                }
            }
            const float bb = bi[tid];
            #pragma unroll
            for (int j = 0; j < 8; ++j) projF[(size_t)(r0 + j) * 256 + tid] = acc[j] + bb;
        }
        if (tid < 128) {
            const int d = tid & 63;
            const float* w = (tid < 64) ? &Wq[d * 256] : &Wk[d * 256];
            float acc[8] = {0.f,0.f,0.f,0.f,0.f,0.f,0.f,0.f};
            for (int i = 0; i < 256; i += 4) {
                f32x4_t ww = *(const f32x4_t*)&w[i];
                #pragma unroll
                for (int j = 0; j < 8; ++j) {
                    const float* x = &sInv8[j][i];
                    acc[j] += ww.x * x[0] + ww.y * x[1] + ww.z * x[2] + ww.w * x[3];
                }
            }
            const float bb = (tid < 64) ? bq[d] : bk[d];
            float* dst = (tid < 64) ? qmsg : kmsg;
            #pragma unroll
            for (int j = 0; j < 8; ++j) dst[(size_t)(r0 + j) * 64 + d] = acc[j] + bb;
        }
        if (tid < 192) {
            const int c = tid >> 6, e = tid & 63;
            const float* w = &Wc[e * 64];
            float acc[8] = {0.f,0.f,0.f,0.f,0.f,0.f,0.f,0.f};
            for (int dd = 0; dd < 64; dd += 4) {
                f32x4_t ww = *(const f32x4_t*)&w[dd];
                #pragma unroll
                for (int j = 0; j < 8; ++j) {
                    const float* x = &sEqu8[j][c * 64 + dd];
                    acc[j] += ww.x * x[0] + ww.y * x[1] + ww.z * x[2] + ww.w * x[3];
                }
            }
            #pragma unroll
            for (int j = 0; j < 8; ++j) projE[(size_t)(r0 + j) * 192 + tid] = acc[j];
        }
    } else if (blk < 144) {
        const int base = (blk - 128) * 4096;
        #pragma unroll
        for (int r = 0; r < 16; ++r) {
            const int idx = base + r * 256 + tid;
            W1bf[idx] = (__bf16)W1[idx];
        }
    } else if (blk < 153) {
        const int base = (blk - 144) * 4096;
        #pragma unroll
        for (int r = 0; r < 16; ++r) {
            const int idx = base + r * 256 + tid;     // idx < 144*256
            const int o = idx >> 8, cc = idx & 255;
            const int src = (o < 64) ? (72 + o) : (o < 136 ? o - 64 : -1);
            W2bf[idx] = (src >= 0) ? (__bf16)W2[src * 256 + cc] : (__bf16)0.f;
        }
    }
}

// ---------------- main fused kernel: one 16-wave workgroup per (b,q) ---------
__global__ __launch_bounds__(1024, 4) void semla_main(
    const float* __restrict__ equis, const float* __restrict__ edges,
    const int* __restrict__ adj,
    const __bf16* __restrict__ W1bf, const __bf16* __restrict__ W2bf,
    const float* __restrict__ qmsg, const float* __restrict__ kmsg,
    const float* __restrict__ projE, const float* __restrict__ projF,
    const float* __restrict__ b1, const float* __restrict__ b2,
    float* __restrict__ outE, float* __restrict__ outI, float* __restrict__ outEdge)
{
    const int bqid = ((blockIdx.x & 7) << 7) | (blockIdx.x >> 3);  // XCD swizzle
    const int b = bqid >> 8;
    const int tid = threadIdx.x;
    const int wave = tid >> 6, lane = tid & 63;
    const int arow = lane & 15, kgrp = lane >> 4;

    __shared__ __align__(16) __bf16 sX[KV * 256];   // 16KB: X tile, H in place
    __shared__ __align__(16) float  sS[KV * SP];    // logits -> p
    __shared__ __align__(16) float  sB1[256];
    __shared__ __align__(16) float  sB2[144];
    __shared__ __align__(16) float  sEquiQ[192];
    __shared__ __align__(16) __bf16 sQm[64];
    __shared__ float sF[72], sL[72], sL2[72];
    __shared__ int   sAdj[KV];

    if (tid < 256) sB1[tid] = b1[tid];
    if (tid < 144) sB2[tid] = (tid < 64) ? b2[72 + tid] : (tid < 136 ? b2[tid - 64] : 0.f);
    if (tid < 192) sEquiQ[tid] = equis[(size_t)bqid * 192 + tid];
    if (tid < 64)  sQm[tid] = (__bf16)qmsg[(size_t)bqid * 64 + tid];

    // ---- hoist weights into registers (loop-invariant) ----
    bf16x8_t w1r[8], w2r[8];
    #pragma unroll
    for (int ks = 0; ks < 8; ++ks)
        w1r[ks] = *(const bf16x8_t*)
            &W1bf[(((wave << 4) + arow) << 8) + ks * 32 + (kgrp << 3)];
    if (wave >= 7) {
        #pragma unroll
        for (int ks = 0; ks < 8; ++ks)
            w2r[ks] = *(const bf16x8_t*)
                &W2bf[((((wave - 7) << 4) + arow) << 8) + ks * 32 + (kgrp << 3)];
    }

    // persistent per-thread state
    float m_run = -1e30f, l_run = 0.f, l2_run = 0.f;   // tid<72
    float accE = 0.f;                                   // tid in [768,960)
    float accI = 0.f;                                   // tid in [512,768)
    const int eidx = tid - 768, c_e = (tid - 768) >> 6, d_e = tid & 63;
    const int fidx = tid - 512, h_i = (tid - 512) >> 5;

    const int seg = tid >> 8, sidx = tid & 255;
    const int rs = sidx >> 3, c8 = (sidx & 7) << 3;     // staging role
    __syncthreads();                        // init LDS visible

    for (int kt = 0; kt < 8; ++kt) {
        const int k0 = kt * KV;
        const int kb = b * 256 + k0;

        // ---- stage X tile [32 rows][qmsg|kmsg|dot|edges], seg-parallel ----
        if (seg == 0) {
            *(bf16x8_t*)&sX[swz(rs, c8)] = *(const bf16x8_t*)&sQm[c8];
        } else if (seg == 1) {
            const float* p = &kmsg[(size_t)(kb + rs) * 64 + c8];
            f32x4_t lo = *(const f32x4_t*)p;
            f32x4_t hi = *(const f32x4_t*)(p + 4);
            *(bf16x8_t*)&sX[swz(rs, 64 + c8)] = cvt8(lo, hi);
        } else if (seg == 2) {
            const float* ek = &equis[(size_t)(kb + rs) * 192 + c8];
            f32x4_t e0a = *(const f32x4_t*)(ek),       e0b = *(const f32x4_t*)(ek + 4);
            f32x4_t e1a = *(const f32x4_t*)(ek + 64),  e1b = *(const f32x4_t*)(ek + 68);
            f32x4_t e2a = *(const f32x4_t*)(ek + 128), e2b = *(const f32x4_t*)(ek + 132);
            f32x4_t q0a = *(const f32x4_t*)&sEquiQ[c8],       q0b = *(const f32x4_t*)&sEquiQ[c8 + 4];
            f32x4_t q1a = *(const f32x4_t*)&sEquiQ[64 + c8],  q1b = *(const f32x4_t*)&sEquiQ[68 + c8];
            f32x4_t q2a = *(const f32x4_t*)&sEquiQ[128 + c8], q2b = *(const f32x4_t*)&sEquiQ[132 + c8];
            f32x4_t da = e0a * q0a + e1a * q1a + e2a * q2a;
            f32x4_t db = e0b * q0b + e1b * q1b + e2b * q2b;
            *(bf16x8_t*)&sX[swz(rs, 128 + c8)] = cvt8(da, db);
        } else {
            const float* p = &edges[((size_t)bqid * 256 + k0 + rs) * 64 + c8];
            f32x4_t lo = *(const f32x4_t*)p;
            f32x4_t hi = *(const f32x4_t*)(p + 4);
            *(bf16x8_t*)&sX[swz(rs, 192 + c8)] = cvt8(lo, hi);
        }
        if (tid < KV) sAdj[tid] = adj[(size_t)bqid * 256 + k0 + tid];
        __syncthreads();                      // (1) X staged

        // ---- GEMM1: wave owns 16 FF cols; W1 from registers ----
        f32x4_t acc1[2];
        {
            const f32x4_t z = {0.f, 0.f, 0.f, 0.f};
            acc1[0] = z; acc1[1] = z;
        }
        #pragma unroll
        for (int ks = 0; ks < 8; ++ks) {
            const int kk = ks * 32 + (kgrp << 3);
            bf16x8_t a0 = *(const bf16x8_t*)&sX[swz(arow, kk)];
            bf16x8_t a1 = *(const bf16x8_t*)&sX[swz(16 + arow, kk)];
            acc1[0] = __builtin_amdgcn_mfma_f32_16x16x32_bf16(a0, w1r[ks], acc1[0], 0, 0, 0);
            acc1[1] = __builtin_amdgcn_mfma_f32_16x16x32_bf16(a1, w1r[ks], acc1[1], 0, 0, 0);
        }
        __syncthreads();                      // (2) all waves done reading X

        // ---- silu -> H (in place over X) ----
        {
            const int ccol = (wave << 4) + arow;
            const float bb = sB1[ccol];
            #pragma unroll
            for (int rt = 0; rt < 2; ++rt)
                #pragma unroll
                for (int j = 0; j < 4; ++j) {
                    const int row = (rt << 4) + (kgrp << 2) + j;
                    float x = acc1[rt][j] + bb;
                    sX[swz(row, ccol)] = (__bf16)(x / (1.f + __expf(-x)));
                }
        }
        __syncthreads();                      // (3) H ready

        // ---- GEMM2: waves 7..15 -> 9 col-tiles; W2 from registers ----
        if (wave >= 7) {
            f32x4_t acc2[2];
            {
                const f32x4_t z = {0.f, 0.f, 0.f, 0.f};
                acc2[0] = z; acc2[1] = z;
            }
            #pragma unroll
            for (int ks = 0; ks < 8; ++ks) {
                const int kk = ks * 32 + (kgrp << 3);
                bf16x8_t a0 = *(const bf16x8_t*)&sX[swz(arow, kk)];
                bf16x8_t a1 = *(const bf16x8_t*)&sX[swz(16 + arow, kk)];
                acc2[0] = __builtin_amdgcn_mfma_f32_16x16x32_bf16(a0, w2r[ks], acc2[0], 0, 0, 0);
                acc2[1] = __builtin_amdgcn_mfma_f32_16x16x32_bf16(a1, w2r[ks], acc2[1], 0, 0, 0);
            }
            const int col = ((wave - 7) << 4) + arow;
            const float bb2 = sB2[col];
            #pragma unroll
            for (int rt = 0; rt < 2; ++rt)
                #pragma unroll
                for (int j = 0; j < 4; ++j) {
                    const int r = (rt << 4) + (kgrp << 2) + j;
                    const float v = acc2[rt][j] + bb2;
                    if (col < 64)
                        outEdge[((size_t)bqid * 256 + k0 + r) * 64 + col] = v;
                    else if (col < 136)
                        sS[r * SP + (col - 64)] = v;
                }
        }
        __syncthreads();                      // (4) logits + adj ready

        // ---- pass A: per-channel online softmax ----
        if (tid < 72) {
            float tm = -1e30f;
            #pragma unroll 8
            for (int k = 0; k < KV; ++k)
                if (sAdj[k]) tm = fmaxf(tm, sS[k * SP + tid]);
            const float mN = fmaxf(m_run, tm);
            const float f = __expf(m_run - mN);
            float s1 = 0.f, s2 = 0.f;
            #pragma unroll 8
            for (int k = 0; k < KV; ++k) {
                float p = sAdj[k] ? __expf(sS[k * SP + tid] - mN) : 0.f;
                sS[k * SP + tid] = p;
                s1 += p; s2 += p * p;
            }
            l_run = l_run * f + s1;
            l2_run = l2_run * f * f + s2;
            m_run = mN;
            sF[tid] = f;
        }
        __syncthreads();                      // (5) p + rescale ready

        // ---- pass B: attention accumulation ----
        if (tid >= 768 && tid < 960) {
            float a = accE * sF[d_e];
            const float* pe = &projE[((size_t)kb * 3 + c_e) * 64 + d_e];
            #pragma unroll
            for (int h = 0; h < 4; ++h) {
                float pr[8];
                #pragma unroll
                for (int t = 0; t < 8; ++t) pr[t] = pe[(h * 8 + t) * 192];
                #pragma unroll
                for (int t = 0; t < 8; ++t) a += sS[(h * 8 + t) * SP + d_e] * pr[t];
            }
            accE = a;
        }
        if (tid >= 512 && tid < 768) {
            float a = accI * sF[64 + h_i];
            const float* pf = &projF[(size_t)kb * 256 + fidx];
            #pragma unroll
            for (int h = 0; h < 4; ++h) {
                float pr[8];
                #pragma unroll
                for (int t = 0; t < 8; ++t) pr[t] = pf[(h * 8 + t) * 256];
                #pragma unroll
                for (int t = 0; t < 8; ++t) a += sS[(h * 8 + t) * SP + 64 + h_i] * pr[t];
            }
            accI = a;
        }
        // next sS/sF writes happen only after >=3 barriers of tile kt+1
    }

    // ---- finalize: write pre-GEMV values in place (post-kernel finishes) ----
    if (tid < 72) { sL[tid] = l_run; sL2[tid] = l2_run; }
    __syncthreads();
    if (tid >= 768 && tid < 960) {
        const float ll = sL[d_e];
        outE[(size_t)bqid * 192 + eidx] = accE * sqrtf(sL2[d_e]) / (ll * ll);
    }
    if (tid >= 512 && tid < 768) {
        const float ll = sL[64 + h_i];
        outI[(size_t)bqid * 256 + fidx] = accI * sqrtf(sL2[64 + h_i]) / (ll * ll);
    }
}

// ---------------- post-kernel: final Wa / Wo GEMVs, in place ----------------
__global__ __launch_bounds__(256) void semla_post(
    const float* __restrict__ Wa, const float* __restrict__ Wo,
    const float* __restrict__ bo,
    float* __restrict__ outE, float* __restrict__ outI)
{
    __shared__ __align__(16) float hE[32][192];
    __shared__ __align__(16) float hI[32][256];
    const int blk = blockIdx.x, tid = threadIdx.x;
    const int r0 = blk * 32;
    for (int r = 0; r < 32; ++r) {
        if (tid < 192) hE[r][tid] = outE[(size_t)(r0 + r) * 192 + tid];
        hI[r][tid] = outI[(size_t)(r0 + r) * 256 + tid];
    }
    __syncthreads();
    if (tid < 192) {                        // equi_updates = hE @ Wa^T
        const int c = tid >> 6, e = tid & 63;
        float wa[64];
        #pragma unroll
        for (int d = 0; d < 64; d += 4) {
            f32x4_t w = *(const f32x4_t*)&Wa[e * 64 + d];
            wa[d] = w.x; wa[d + 1] = w.y; wa[d + 2] = w.z; wa[d + 3] = w.w;
        }
        for (int r = 0; r < 32; ++r) {
            float s = 0.f;
            #pragma unroll
            for (int d = 0; d < 64; ++d) s += hE[r][c * 64 + d] * wa[d];
            outE[((size_t)(r0 + r) * 3 + c) * 64 + e] = s;
        }
    }
    {                                       // inv_updates = hI @ Wo^T + bo
        const float bb = bo[tid];
        const float* wo = &Wo[tid * 256];
        for (int r = 0; r < 32; ++r) {
            float s = 0.f;
            for (int i = 0; i < 256; i += 4) {
                f32x4_t w = *(const f32x4_t*)&wo[i];
                s += w.x * hI[r][i] + w.y * hI[r][i + 1]
                   + w.z * hI[r][i + 2] + w.w * hI[r][i + 3];
            }
            outI[(size_t)(r0 + r) * 256 + tid] = s + bb;
        }
    }
}

extern "C" void kernel_launch(void* const* d_in, const int* in_sizes, int n_in,
                              void* d_out, int out_size, void* d_ws, size_t ws_size,
                              hipStream_t stream) {
    (void)in_sizes; (void)n_in; (void)out_size; (void)ws_size;
    const float* equis = (const float*)d_in[0];
    const float* invs  = (const float*)d_in[1];
    const float* edges = (const float*)d_in[2];
    const int*   adj   = (const int*)d_in[3];
    const float* Wq = (const float*)d_in[4];
    const float* bq = (const float*)d_in[5];
    const float* Wk = (const float*)d_in[6];
    const float* bk = (const float*)d_in[7];
    const float* W1 = (const float*)d_in[8];
    const float* b1 = (const float*)d_in[9];
    const float* W2 = (const float*)d_in[10];
    const float* b2 = (const float*)d_in[11];
    const float* Wc = (const float*)d_in[12];
    const float* Wa = (const float*)d_in[13];
    const float* Wi = (const float*)d_in[14];
    const float* bi = (const float*)d_in[15];
    const float* Wo = (const float*)d_in[16];
    const float* bo = (const float*)d_in[17];

    float* out = (float*)d_out;
    float* outE    = out;                  // (B,N,3,64)  = 196608
    float* outI    = out + 196608;         // (B,N,256)   = 262144
    float* outEdge = out + 458752;         // (B,N,N,64)  = 16777216

    char* ws = (char*)d_ws;
    __bf16* W1bf = (__bf16*)(ws);                    // 131072 B
    __bf16* W2bf = (__bf16*)(ws + 131072);           //  73728 B
    float* qmsg  = (float*)(ws + 204800);            // 262144 B
    float* kmsg  = (float*)(ws + 466944);            // 262144 B
    float* projE = (float*)(ws + 729088);            // 786432 B
    float* projF = (float*)(ws + 1515520);           // 1048576 B

    semla_pre<<<153, 256, 0, stream>>>(invs, equis, Wq, bq, Wk, bk, Wc, Wi, bi,
                                       W1, W2, W1bf, W2bf, qmsg, kmsg, projE, projF);
    semla_main<<<1024, 1024, 0, stream>>>(equis, edges, adj, W1bf, W2bf, qmsg, kmsg,
                                          projE, projF, b1, b2,
                                          outE, outI, outEdge);
    semla_post<<<32, 256, 0, stream>>>(Wa, Wo, bo, outE, outI);
}

// Round 8
// 459.358 us; speedup vs baseline: 2.2345x; 1.3440x over previous
//
#include <hip/hip_runtime.h>
#include <hip/hip_bf16.h>
#include <cstdint>

// SemlaLayer fused forward for MI355X (gfx950).
// R8: true register residency. 512-thr/8-wave main blocks (256-VGPR budget,
// launch_bounds(512,2)); qmsg folded into per-(b,q) bias qc (GEMM1 K=192);
// 4 barriers/tile with passB merged under stage; pre/post parallelized.

typedef __bf16 bf16x8_t __attribute__((ext_vector_type(8)));
typedef float  f32x4_t  __attribute__((ext_vector_type(4)));

#define SP 76   // sS pitch in floats
#define KV 32   // k-tile rows

__device__ __forceinline__ int swz(int row, int col) {
    // element-index XOR swizzle at 8-element (16B) granularity (G4); pitch 256.
    return (row << 8) + (col ^ ((row & 7) << 3));
}

__device__ __forceinline__ bf16x8_t cvt8(f32x4_t a, f32x4_t b) {
    bf16x8_t r;
    r[0] = (__bf16)a.x; r[1] = (__bf16)a.y; r[2] = (__bf16)a.z; r[3] = (__bf16)a.w;
    r[4] = (__bf16)b.x; r[5] = (__bf16)b.y; r[6] = (__bf16)b.z; r[7] = (__bf16)b.w;
    return r;
}

// ---------------- pre-kernel ----------------
// blocks 0..255  : 4 (b,n) rows each -> kmsg, projE, projF, qc
// blocks 256..267: W1bf conversion (256x192, input cols 64..255 of W1)
// blocks 268..276: W2bf conversion (144x256, rows reordered: edge|logit|pad)
__global__ __launch_bounds__(256) void semla_pre(
    const float* __restrict__ invs, const float* __restrict__ equis,
    const float* __restrict__ Wq, const float* __restrict__ bq,
    const float* __restrict__ Wk, const float* __restrict__ bk,
    const float* __restrict__ Wc, const float* __restrict__ Wi, const float* __restrict__ bi,
    const float* __restrict__ W1, const float* __restrict__ b1,
    const float* __restrict__ W2,
    __bf16* __restrict__ W1bf, __bf16* __restrict__ W2bf,
    float* __restrict__ qc, float* __restrict__ kmsg,
    float* __restrict__ projE, float* __restrict__ projF)
{
    const int blk = blockIdx.x, tid = threadIdx.x;
    if (blk < 256) {
        const int r0 = blk * 4;
        __shared__ __align__(16) float sInv4[4][256];
        __shared__ __align__(16) float sEqu4[4][192];
        __shared__ __align__(16) float sQm4[4][64];
        #pragma unroll
        for (int j = 0; j < 4; ++j) {
            sInv4[j][tid] = invs[(size_t)(r0 + j) * 256 + tid];
            if (tid < 192) sEqu4[j][tid] = equis[(size_t)(r0 + j) * 192 + tid];
        }
        __syncthreads();
        {   // projF = invs @ Wi.T + bi
            float acc[4] = {0.f, 0.f, 0.f, 0.f};
            const float* w = &Wi[tid * 256];
            for (int i = 0; i < 256; i += 4) {
                f32x4_t ww = *(const f32x4_t*)&w[i];
                #pragma unroll
                for (int j = 0; j < 4; ++j) {
                    const float* x = &sInv4[j][i];
                    acc[j] += ww.x * x[0] + ww.y * x[1] + ww.z * x[2] + ww.w * x[3];
                }
            }
            const float bb = bi[tid];
            #pragma unroll
            for (int j = 0; j < 4; ++j) projF[(size_t)(r0 + j) * 256 + tid] = acc[j] + bb;
        }
        if (tid < 128) {   // qmsg (to LDS) / kmsg (to global)
            const int d = tid & 63;
            const float* w = (tid < 64) ? &Wq[d * 256] : &Wk[d * 256];
            float acc[4] = {0.f, 0.f, 0.f, 0.f};
            for (int i = 0; i < 256; i += 4) {
                f32x4_t ww = *(const f32x4_t*)&w[i];
                #pragma unroll
                for (int j = 0; j < 4; ++j) {
                    const float* x = &sInv4[j][i];
                    acc[j] += ww.x * x[0] + ww.y * x[1] + ww.z * x[2] + ww.w * x[3];
                }
            }
            if (tid < 64) {
                const float bb = bq[d];
                #pragma unroll
                for (int j = 0; j < 4; ++j) sQm4[j][d] = acc[j] + bb;
            } else {
                const float bb = bk[d];
                #pragma unroll
                for (int j = 0; j < 4; ++j) kmsg[(size_t)(r0 + j) * 64 + d] = acc[j] + bb;
            }
        }
        if (tid < 192) {   // projE = equis @ Wc.T
            const int c = tid >> 6, e = tid & 63;
            const float* w = &Wc[e * 64];
            float acc[4] = {0.f, 0.f, 0.f, 0.f};
            for (int dd = 0; dd < 64; dd += 4) {
                f32x4_t ww = *(const f32x4_t*)&w[dd];
                #pragma unroll
                for (int j = 0; j < 4; ++j) {
                    const float* x = &sEqu4[j][c * 64 + dd];
                    acc[j] += ww.x * x[0] + ww.y * x[1] + ww.z * x[2] + ww.w * x[3];
                }
            }
            #pragma unroll
            for (int j = 0; j < 4; ++j) projE[(size_t)(r0 + j) * 192 + tid] = acc[j];
        }
        __syncthreads();   // sQm4 ready
        {   // qc[r][o] = sum_{d<64} W1[o][d] * qmsg[r][d]
            const float* w = &W1[tid * 256];
            float acc[4] = {0.f, 0.f, 0.f, 0.f};
            for (int d = 0; d < 64; d += 4) {
                f32x4_t ww = *(const f32x4_t*)&w[d];
                #pragma unroll
                for (int j = 0; j < 4; ++j) {
                    const float* x = &sQm4[j][d];
                    acc[j] += ww.x * x[0] + ww.y * x[1] + ww.z * x[2] + ww.w * x[3];
                }
            }
            #pragma unroll
            for (int j = 0; j < 4; ++j) qc[(size_t)(r0 + j) * 256 + tid] = acc[j];
        }
    } else if (blk < 268) {   // W1bf: 256x192, source col 64+k
        const int base = (blk - 256) * 4096;
        #pragma unroll
        for (int it = 0; it < 16; ++it) {
            const int e = base + it * 256 + tid;   // < 49152
            const int o = e / 192, k = e % 192;
            W1bf[e] = (__bf16)W1[o * 256 + 64 + k];
        }
    } else if (blk < 277) {   // W2bf reordered: rows 0-63 = edge(72..135), 64-135 = logit(0..71)
        const int base = (blk - 268) * 4096;
        #pragma unroll
        for (int it = 0; it < 16; ++it) {
            const int e = base + it * 256 + tid;   // < 36864
            const int o = e >> 8, cc = e & 255;
            const int src = (o < 64) ? (72 + o) : (o < 136 ? o - 64 : -1);
            W2bf[e] = (src >= 0) ? (__bf16)W2[src * 256 + cc] : (__bf16)0.f;
        }
    }
}

// ---------------- main fused kernel: one 8-wave workgroup per (b,q) ---------
__global__ __launch_bounds__(512, 2) void semla_main(
    const float* __restrict__ equis, const float* __restrict__ edges,
    const int* __restrict__ adj,
    const __bf16* __restrict__ W1bf, const __bf16* __restrict__ W2bf,
    const float* __restrict__ qc, const float* __restrict__ kmsg,
    const float* __restrict__ projE, const float* __restrict__ projF,
    const float* __restrict__ b1, const float* __restrict__ b2,
    float* __restrict__ outE, float* __restrict__ outI, float* __restrict__ outEdge)
{
    const int bqid = ((blockIdx.x & 7) << 7) | (blockIdx.x >> 3);  // XCD swizzle
    const int b = bqid >> 8;
    const int tid = threadIdx.x;
    const int wave = tid >> 6, lane = tid & 63;
    const int arow = lane & 15, kgrp = lane >> 4;

    __shared__ __align__(16) __bf16 sX[KV * 256];   // X tile (cols 0..191 used)
    __shared__ __align__(16) __bf16 sH[KV * 256];   // H tile
    __shared__ __align__(16) float  sS[KV * SP];    // logits -> p
    __shared__ __align__(16) float  sB1[256];
    __shared__ __align__(16) float  sB2[144];
    __shared__ __align__(16) float  sEquiQ[192];
    __shared__ float sF[72], sL[72], sL2[72];
    __shared__ int   sAdj[KV];

    if (tid < 256) sB1[tid] = b1[tid] + qc[(size_t)bqid * 256 + tid];
    if (tid < 144) sB2[tid] = (tid < 64) ? b2[72 + tid] : (tid < 136 ? b2[tid - 64] : 0.f);
    if (tid < 192) sEquiQ[tid] = equis[(size_t)bqid * 192 + tid];

    // ---- loop-invariant weights in registers ----
    bf16x8_t w1r[6][2];                 // 32 FF cols per wave, K=192
    #pragma unroll
    for (int ks = 0; ks < 6; ++ks)
        #pragma unroll
        for (int cf = 0; cf < 2; ++cf)
            w1r[ks][cf] = *(const bf16x8_t*)
                &W1bf[((wave << 5) + (cf << 4) + arow) * 192 + ks * 32 + (kgrp << 3)];
    bf16x8_t w2r[8], w2r2[8];           // wave w: tile w; wave 7: + tile 8
    #pragma unroll
    for (int ks = 0; ks < 8; ++ks)
        w2r[ks] = *(const bf16x8_t*)
            &W2bf[(((wave << 4) + arow) << 8) + ks * 32 + (kgrp << 3)];
    if (wave == 7) {
        #pragma unroll
        for (int ks = 0; ks < 8; ++ks)
            w2r2[ks] = *(const bf16x8_t*)
                &W2bf[((128 + arow) << 8) + ks * 32 + (kgrp << 3)];
    }

    // persistent per-thread state
    float m_run = -1e30f, l_run = 0.f, l2_run = 0.f;   // tid<72
    float accE = 0.f;                                   // tid<192: (c_e,d_e)
    float accI = 0.f;                                   // tid>=256: fidx
    const int c_e = tid >> 6, d_e = tid & 63;
    const int fidx = tid - 256, h_i = (tid - 256) >> 5;

    __syncthreads();                       // init LDS visible

    for (int kt = 0; kt < 8; ++kt) {
        const int k0 = kt * KV;
        const int kb = b * 256 + k0;

        // ---- phase 1: stage X[kt] (+adj) and passB(kt-1) ----
        #pragma unroll
        for (int gi = 0; gi < 2; ++gi) {
            int g;
            if (gi == 0) g = tid;
            else { if (tid < 192 || tid >= 448) continue; g = 512 + (tid - 192); }
            if (g < 768) {
                const int row = g / 24, c8 = (g % 24) << 3;
                if (c8 < 64) {
                    const float* p = &kmsg[(size_t)(kb + row) * 64 + c8];
                    *(bf16x8_t*)&sX[swz(row, c8)] =
                        cvt8(*(const f32x4_t*)p, *(const f32x4_t*)(p + 4));
                } else if (c8 < 128) {
                    const int d0 = c8 - 64;
                    const float* ek = &equis[(size_t)(kb + row) * 192 + d0];
                    f32x4_t e0a = *(const f32x4_t*)(ek),       e0b = *(const f32x4_t*)(ek + 4);
                    f32x4_t e1a = *(const f32x4_t*)(ek + 64),  e1b = *(const f32x4_t*)(ek + 68);
                    f32x4_t e2a = *(const f32x4_t*)(ek + 128), e2b = *(const f32x4_t*)(ek + 132);
                    f32x4_t q0a = *(const f32x4_t*)&sEquiQ[d0],       q0b = *(const f32x4_t*)&sEquiQ[d0 + 4];
                    f32x4_t q1a = *(const f32x4_t*)&sEquiQ[64 + d0],  q1b = *(const f32x4_t*)&sEquiQ[68 + d0];
                    f32x4_t q2a = *(const f32x4_t*)&sEquiQ[128 + d0], q2b = *(const f32x4_t*)&sEquiQ[132 + d0];
                    *(bf16x8_t*)&sX[swz(row, c8)] =
                        cvt8(e0a * q0a + e1a * q1a + e2a * q2a,
                             e0b * q0b + e1b * q1b + e2b * q2b);
                } else {
                    const float* p = &edges[((size_t)bqid * 256 + k0 + row) * 64 + (c8 - 128)];
                    *(bf16x8_t*)&sX[swz(row, c8)] =
                        cvt8(*(const f32x4_t*)p, *(const f32x4_t*)(p + 4));
                }
            }
        }
        if (tid < KV) sAdj[tid] = adj[(size_t)bqid * 256 + k0 + tid];
        if (kt > 0) {
            const int kbP = kb - KV;
            if (tid < 192) {
                float a = accE * sF[d_e];
                const float* pe = &projE[((size_t)kbP * 3 + c_e) * 64 + d_e];
                #pragma unroll
                for (int h = 0; h < 4; ++h) {
                    float pr[8];
                    #pragma unroll
                    for (int t = 0; t < 8; ++t) pr[t] = pe[(h * 8 + t) * 192];
                    #pragma unroll
                    for (int t = 0; t < 8; ++t) a += sS[(h * 8 + t) * SP + d_e] * pr[t];
                }
                accE = a;
            }
            if (tid >= 256) {
                float a = accI * sF[64 + h_i];
                const float* pf = &projF[(size_t)kbP * 256 + fidx];
                #pragma unroll
                for (int h = 0; h < 4; ++h) {
                    float pr[8];
                    #pragma unroll
                    for (int t = 0; t < 8; ++t) pr[t] = pf[(h * 8 + t) * 256];
                    #pragma unroll
                    for (int t = 0; t < 8; ++t) a += sS[(h * 8 + t) * SP + 64 + h_i] * pr[t];
                }
                accI = a;
            }
        }
        __syncthreads();                   // (A) X staged, passB done

        // ---- phase 2: GEMM1 (K=192, W1 in regs) + silu -> sH ----
        f32x4_t acc1[2][2];
        {
            const f32x4_t z = {0.f, 0.f, 0.f, 0.f};
            acc1[0][0] = z; acc1[0][1] = z; acc1[1][0] = z; acc1[1][1] = z;
        }
        #pragma unroll
        for (int ks = 0; ks < 6; ++ks) {
            const int kk = ks * 32 + (kgrp << 3);
            bf16x8_t a0 = *(const bf16x8_t*)&sX[swz(arow, kk)];
            bf16x8_t a1 = *(const bf16x8_t*)&sX[swz(16 + arow, kk)];
            acc1[0][0] = __builtin_amdgcn_mfma_f32_16x16x32_bf16(a0, w1r[ks][0], acc1[0][0], 0, 0, 0);
            acc1[0][1] = __builtin_amdgcn_mfma_f32_16x16x32_bf16(a0, w1r[ks][1], acc1[0][1], 0, 0, 0);
            acc1[1][0] = __builtin_amdgcn_mfma_f32_16x16x32_bf16(a1, w1r[ks][0], acc1[1][0], 0, 0, 0);
            acc1[1][1] = __builtin_amdgcn_mfma_f32_16x16x32_bf16(a1, w1r[ks][1], acc1[1][1], 0, 0, 0);
        }
        #pragma unroll
        for (int rt = 0; rt < 2; ++rt)
            #pragma unroll
            for (int cf = 0; cf < 2; ++cf) {
                const int ccol = (wave << 5) + (cf << 4) + arow;
                const float bb = sB1[ccol];
                #pragma unroll
                for (int j = 0; j < 4; ++j) {
                    const int row = (rt << 4) + (kgrp << 2) + j;
                    float x = acc1[rt][cf][j] + bb;
                    sH[swz(row, ccol)] = (__bf16)(x / (1.f + __expf(-x)));
                }
            }
        __syncthreads();                   // (B) H ready

        // ---- phase 3: GEMM2 (W2 in regs) -> edge stores + logits ----
        f32x4_t acc2[2], acc2b[2];
        {
            const f32x4_t z = {0.f, 0.f, 0.f, 0.f};
            acc2[0] = z; acc2[1] = z; acc2b[0] = z; acc2b[1] = z;
        }
        #pragma unroll
        for (int ks = 0; ks < 8; ++ks) {
            const int kk = ks * 32 + (kgrp << 3);
            bf16x8_t a0 = *(const bf16x8_t*)&sH[swz(arow, kk)];
            bf16x8_t a1 = *(const bf16x8_t*)&sH[swz(16 + arow, kk)];
            acc2[0] = __builtin_amdgcn_mfma_f32_16x16x32_bf16(a0, w2r[ks], acc2[0], 0, 0, 0);
            acc2[1] = __builtin_amdgcn_mfma_f32_16x16x32_bf16(a1, w2r[ks], acc2[1], 0, 0, 0);
            if (wave == 7) {
                acc2b[0] = __builtin_amdgcn_mfma_f32_16x16x32_bf16(a0, w2r2[ks], acc2b[0], 0, 0, 0);
                acc2b[1] = __builtin_amdgcn_mfma_f32_16x16x32_bf16(a1, w2r2[ks], acc2b[1], 0, 0, 0);
            }
        }
        {
            const int col = (wave << 4) + arow;
            const float bb2 = sB2[col];
            #pragma unroll
            for (int rt = 0; rt < 2; ++rt)
                #pragma unroll
                for (int j = 0; j < 4; ++j) {
                    const int r = (rt << 4) + (kgrp << 2) + j;
                    const float v = acc2[rt][j] + bb2;
                    if (col < 64)
                        outEdge[((size_t)bqid * 256 + k0 + r) * 64 + col] = v;
                    else
                        sS[r * SP + (col - 64)] = v;
                }
            if (wave == 7 && arow < 8) {
                const float bb3 = sB2[128 + arow];
                #pragma unroll
                for (int rt = 0; rt < 2; ++rt)
                    #pragma unroll
                    for (int j = 0; j < 4; ++j) {
                        const int r = (rt << 4) + (kgrp << 2) + j;
                        sS[r * SP + 64 + arow] = acc2b[rt][j] + bb3;
                    }
            }
        }
        __syncthreads();                   // (C) logits + adj ready

        // ---- phase 4: per-channel online softmax ----
        if (tid < 72) {
            float tm = -1e30f;
            #pragma unroll 8
            for (int k = 0; k < KV; ++k)
                if (sAdj[k]) tm = fmaxf(tm, sS[k * SP + tid]);
            const float mN = fmaxf(m_run, tm);
            const float f = __expf(m_run - mN);
            float s1 = 0.f, s2 = 0.f;
            #pragma unroll 8
            for (int k = 0; k < KV; ++k) {
                float p = sAdj[k] ? __expf(sS[k * SP + tid] - mN) : 0.f;
                sS[k * SP + tid] = p;
                s1 += p; s2 += p * p;
            }
            l_run = l_run * f + s1;
            l2_run = l2_run * f * f + s2;
            m_run = mN;
            sF[tid] = f;
        }
        __syncthreads();                   // (D) p + rescale ready
    }

    // ---- final passB (kt=7 tile) ----
    {
        const int kbP = b * 256 + 224;
        if (tid < 192) {
            float a = accE * sF[d_e];
            const float* pe = &projE[((size_t)kbP * 3 + c_e) * 64 + d_e];
            #pragma unroll
            for (int h = 0; h < 4; ++h) {
                float pr[8];
                #pragma unroll
                for (int t = 0; t < 8; ++t) pr[t] = pe[(h * 8 + t) * 192];
                #pragma unroll
                for (int t = 0; t < 8; ++t) a += sS[(h * 8 + t) * SP + d_e] * pr[t];
            }
            accE = a;
        }
        if (tid >= 256) {
            float a = accI * sF[64 + h_i];
            const float* pf = &projF[(size_t)kbP * 256 + fidx];
            #pragma unroll
            for (int h = 0; h < 4; ++h) {
                float pr[8];
                #pragma unroll
                for (int t = 0; t < 8; ++t) pr[t] = pf[(h * 8 + t) * 256];
                #pragma unroll
                for (int t = 0; t < 8; ++t) a += sS[(h * 8 + t) * SP + 64 + h_i] * pr[t];
            }
            accI = a;
        }
    }

    // ---- finalize: pre-GEMV outputs (post-kernel applies Wa/Wo) ----
    if (tid < 72) { sL[tid] = l_run; sL2[tid] = l2_run; }
    __syncthreads();
    if (tid < 192) {
        const float ll = sL[d_e];
        outE[(size_t)bqid * 192 + tid] = accE * sqrtf(sL2[d_e]) / (ll * ll);
    }
    if (tid >= 256) {
        const float ll = sL[64 + h_i];
        outI[(size_t)bqid * 256 + fidx] = accI * sqrtf(sL2[64 + h_i]) / (ll * ll);
    }
}

// ---------------- post-kernel: final Wa / Wo GEMVs, in place ----------------
__global__ __launch_bounds__(256) void semla_post(
    const float* __restrict__ Wa, const float* __restrict__ Wo,
    const float* __restrict__ bo,
    float* __restrict__ outE, float* __restrict__ outI)
{
    __shared__ __align__(16) float hE[8][192];
    __shared__ __align__(16) float hI[8][256];
    const int blk = blockIdx.x, tid = threadIdx.x;
    const int r0 = blk * 8;
    #pragma unroll
    for (int r = 0; r < 8; ++r) {
        if (tid < 192) hE[r][tid] = outE[(size_t)(r0 + r) * 192 + tid];
        hI[r][tid] = outI[(size_t)(r0 + r) * 256 + tid];
    }
    __syncthreads();
    if (tid < 192) {                        // equi_updates = hE @ Wa^T
        const int c = tid >> 6, e = tid & 63;
        float wa[64];
        #pragma unroll
        for (int d = 0; d < 64; d += 4) {
            f32x4_t w = *(const f32x4_t*)&Wa[e * 64 + d];
            wa[d] = w.x; wa[d + 1] = w.y; wa[d + 2] = w.z; wa[d + 3] = w.w;
        }
        #pragma unroll
        for (int r = 0; r < 8; ++r) {
            float s = 0.f;
            #pragma unroll
            for (int d = 0; d < 64; ++d) s += hE[r][c * 64 + d] * wa[d];
            outE[((size_t)(r0 + r) * 3 + c) * 64 + e] = s;
        }
    }
    {                                       // inv_updates = hI @ Wo^T + bo
        const float bb = bo[tid];
        const float* wo = &Wo[tid * 256];
        #pragma unroll
        for (int r = 0; r < 8; ++r) {
            float s = 0.f;
            for (int i = 0; i < 256; i += 4) {
                f32x4_t w = *(const f32x4_t*)&wo[i];
                s += w.x * hI[r][i] + w.y * hI[r][i + 1]
                   + w.z * hI[r][i + 2] + w.w * hI[r][i + 3];
            }
            outI[(size_t)(r0 + r) * 256 + tid] = s + bb;
        }
    }
}

extern "C" void kernel_launch(void* const* d_in, const int* in_sizes, int n_in,
                              void* d_out, int out_size, void* d_ws, size_t ws_size,
                              hipStream_t stream) {
    (void)in_sizes; (void)n_in; (void)out_size; (void)ws_size;
    const float* equis = (const float*)d_in[0];
    const float* invs  = (const float*)d_in[1];
    const float* edges = (const float*)d_in[2];
    const int*   adj   = (const int*)d_in[3];
    const float* Wq = (const float*)d_in[4];
    const float* bq = (const float*)d_in[5];
    const float* Wk = (const float*)d_in[6];
    const float* bk = (const float*)d_in[7];
    const float* W1 = (const float*)d_in[8];
    const float* b1 = (const float*)d_in[9];
    const float* W2 = (const float*)d_in[10];
    const float* b2 = (const float*)d_in[11];
    const float* Wc = (const float*)d_in[12];
    const float* Wa = (const float*)d_in[13];
    const float* Wi = (const float*)d_in[14];
    const float* bi = (const float*)d_in[15];
    const float* Wo = (const float*)d_in[16];
    const float* bo = (const float*)d_in[17];

    float* out = (float*)d_out;
    float* outE    = out;                  // (B,N,3,64)  = 196608
    float* outI    = out + 196608;         // (B,N,256)   = 262144
    float* outEdge = out + 458752;         // (B,N,N,64)  = 16777216

    char* ws = (char*)d_ws;
    __bf16* W1bf = (__bf16*)(ws);                    //  98304 B (256x192)
    __bf16* W2bf = (__bf16*)(ws + 98304);            //  73728 B (144x256)
    float* qc    = (float*)(ws + 172032);            // 1048576 B
    float* kmsg  = (float*)(ws + 1220608);           //  262144 B
    float* projE = (float*)(ws + 1482752);           //  786432 B
    float* projF = (float*)(ws + 2269184);           // 1048576 B -> 3317760 total

    semla_pre<<<277, 256, 0, stream>>>(invs, equis, Wq, bq, Wk, bk, Wc, Wi, bi,
                                       W1, b1, W2, W1bf, W2bf, qc, kmsg, projE, projF);
    semla_main<<<1024, 512, 0, stream>>>(equis, edges, adj, W1bf, W2bf, qc, kmsg,
                                         projE, projF, b1, b2,
                                         outE, outI, outEdge);
    semla_post<<<128, 256, 0, stream>>>(Wa, Wo, bo, outE, outI);
}

// Round 9
// 299.521 us; speedup vs baseline: 3.4269x; 1.5336x over previous
//
#include <hip/hip_runtime.h>
#include <hip/hip_bf16.h>
#include <cstdint>

// SemlaLayer fused forward for MI355X (gfx950).
// R9: in-register softmax inside GEMM2 wave (3 barriers/tile, no serial
// softmax phase); projE/projF transposed for coalesced passB; post 256 blocks.

typedef __bf16 bf16x8_t __attribute__((ext_vector_type(8)));
typedef float  f32x4_t  __attribute__((ext_vector_type(4)));

#define SP 76   // sS pitch in floats
#define KV 32   // k-tile rows

__device__ __forceinline__ int swzX(int row, int col) {   // pitch 192
    return row * 192 + (col ^ ((row & 7) << 3));
}
__device__ __forceinline__ int swzH(int row, int col) {   // pitch 256
    return (row << 8) + (col ^ ((row & 7) << 3));
}

__device__ __forceinline__ bf16x8_t cvt8(f32x4_t a, f32x4_t b) {
    bf16x8_t r;
    r[0] = (__bf16)a.x; r[1] = (__bf16)a.y; r[2] = (__bf16)a.z; r[3] = (__bf16)a.w;
    r[4] = (__bf16)b.x; r[5] = (__bf16)b.y; r[6] = (__bf16)b.z; r[7] = (__bf16)b.w;
    return r;
}

// ---------------- pre-kernel ----------------
// blocks 0..255  : 4 (b,n) rows each -> kmsg, pTE, pTF (transposed), qc
// blocks 256..267: W1bf (256x192, W1 cols 64..255)
// blocks 268..276: W2bf (144x256, rows reordered: edge(72..135)|logit(0..71)|pad)
__global__ __launch_bounds__(256) void semla_pre(
    const float* __restrict__ invs, const float* __restrict__ equis,
    const float* __restrict__ Wq, const float* __restrict__ bq,
    const float* __restrict__ Wk, const float* __restrict__ bk,
    const float* __restrict__ Wc, const float* __restrict__ Wi, const float* __restrict__ bi,
    const float* __restrict__ W1, const float* __restrict__ W2,
    __bf16* __restrict__ W1bf, __bf16* __restrict__ W2bf,
    float* __restrict__ qc, float* __restrict__ kmsg,
    float* __restrict__ pTE, float* __restrict__ pTF)
{
    const int blk = blockIdx.x, tid = threadIdx.x;
    if (blk < 256) {
        const int r0 = blk * 4;
        __shared__ __align__(16) float sInv4[4][256];
        __shared__ __align__(16) float sEqu4[4][192];
        __shared__ __align__(16) float sQm4[4][64];
        #pragma unroll
        for (int j = 0; j < 4; ++j) {
            sInv4[j][tid] = invs[(size_t)(r0 + j) * 256 + tid];
            if (tid < 192) sEqu4[j][tid] = equis[(size_t)(r0 + j) * 192 + tid];
        }
        __syncthreads();
        {   // projF = invs @ Wi.T + bi  -> pTF[b][f][n]
            float acc[4] = {0.f, 0.f, 0.f, 0.f};
            const float* w = &Wi[tid * 256];
            for (int i = 0; i < 256; i += 4) {
                f32x4_t ww = *(const f32x4_t*)&w[i];
                #pragma unroll
                for (int j = 0; j < 4; ++j) {
                    const float* x = &sInv4[j][i];
                    acc[j] += ww.x * x[0] + ww.y * x[1] + ww.z * x[2] + ww.w * x[3];
                }
            }
            const float bb = bi[tid];
            #pragma unroll
            for (int j = 0; j < 4; ++j) {
                const int bb_ = (r0 + j) >> 8, nl = (r0 + j) & 255;
                pTF[((size_t)bb_ * 256 + tid) * 256 + nl] = acc[j] + bb;
            }
        }
        if (tid < 128) {   // qmsg (to LDS) / kmsg (to global)
            const int d = tid & 63;
            const float* w = (tid < 64) ? &Wq[d * 256] : &Wk[d * 256];
            float acc[4] = {0.f, 0.f, 0.f, 0.f};
            for (int i = 0; i < 256; i += 4) {
                f32x4_t ww = *(const f32x4_t*)&w[i];
                #pragma unroll
                for (int j = 0; j < 4; ++j) {
                    const float* x = &sInv4[j][i];
                    acc[j] += ww.x * x[0] + ww.y * x[1] + ww.z * x[2] + ww.w * x[3];
                }
            }
            if (tid < 64) {
                const float bb = bq[d];
                #pragma unroll
                for (int j = 0; j < 4; ++j) sQm4[j][d] = acc[j] + bb;
            } else {
                const float bb = bk[d];
                #pragma unroll
                for (int j = 0; j < 4; ++j) kmsg[(size_t)(r0 + j) * 64 + d] = acc[j] + bb;
            }
        }
        if (tid < 192) {   // projE = equis @ Wc.T -> pTE[b][c][d][n]
            const int c = tid >> 6, e = tid & 63;
            const float* w = &Wc[e * 64];
            float acc[4] = {0.f, 0.f, 0.f, 0.f};
            for (int dd = 0; dd < 64; dd += 4) {
                f32x4_t ww = *(const f32x4_t*)&w[dd];
                #pragma unroll
                for (int j = 0; j < 4; ++j) {
                    const float* x = &sEqu4[j][c * 64 + dd];
                    acc[j] += ww.x * x[0] + ww.y * x[1] + ww.z * x[2] + ww.w * x[3];
                }
            }
            #pragma unroll
            for (int j = 0; j < 4; ++j) {
                const int bb_ = (r0 + j) >> 8, nl = (r0 + j) & 255;
                pTE[(((size_t)bb_ * 3 + c) * 64 + e) * 256 + nl] = acc[j];
            }
        }
        __syncthreads();   // sQm4 ready
        {   // qc[r][o] = sum_{d<64} W1[o][d] * qmsg[r][d]
            const float* w = &W1[tid * 256];
            float acc[4] = {0.f, 0.f, 0.f, 0.f};
            for (int d = 0; d < 64; d += 4) {
                f32x4_t ww = *(const f32x4_t*)&w[d];
                #pragma unroll
                for (int j = 0; j < 4; ++j) {
                    const float* x = &sQm4[j][d];
                    acc[j] += ww.x * x[0] + ww.y * x[1] + ww.z * x[2] + ww.w * x[3];
                }
            }
            #pragma unroll
            for (int j = 0; j < 4; ++j) qc[(size_t)(r0 + j) * 256 + tid] = acc[j];
        }
    } else if (blk < 268) {   // W1bf: 256x192, source col 64+k
        const int base = (blk - 256) * 4096;
        #pragma unroll
        for (int it = 0; it < 16; ++it) {
            const int e = base + it * 256 + tid;   // < 49152
            const int o = e / 192, k = e % 192;
            W1bf[e] = (__bf16)W1[o * 256 + 64 + k];
        }
    } else if (blk < 277) {   // W2bf reordered
        const int base = (blk - 268) * 4096;
        #pragma unroll
        for (int it = 0; it < 16; ++it) {
            const int e = base + it * 256 + tid;   // < 36864
            const int o = e >> 8, cc = e & 255;
            const int src = (o < 64) ? (72 + o) : (o < 136 ? o - 64 : -1);
            W2bf[e] = (src >= 0) ? (__bf16)W2[src * 256 + cc] : (__bf16)0.f;
        }
    }
}

// ---------------- main fused kernel: one 8-wave workgroup per (b,q) ---------
__global__ __launch_bounds__(512, 2) void semla_main(
    const float* __restrict__ equis, const float* __restrict__ edges,
    const int* __restrict__ adj,
    const __bf16* __restrict__ W1bf, const __bf16* __restrict__ W2bf,
    const float* __restrict__ qc, const float* __restrict__ kmsg,
    const float* __restrict__ pTE, const float* __restrict__ pTF,
    const float* __restrict__ b1, const float* __restrict__ b2,
    float* __restrict__ outE, float* __restrict__ outI, float* __restrict__ outEdge)
{
    const int bqid = ((blockIdx.x & 7) << 7) | (blockIdx.x >> 3);  // XCD swizzle
    const int b = bqid >> 8;
    const int tid = threadIdx.x;
    const int wave = tid >> 6, lane = tid & 63;
    const int arow = lane & 15, kgrp = lane >> 4;

    __shared__ __align__(16) __bf16 sX[KV * 192];   // 12KB X tile (K=192)
    __shared__ __align__(16) __bf16 sH[KV * 256];   // 16KB H tile
    __shared__ __align__(16) float  sS[KV * SP];    // p values
    __shared__ __align__(16) float  sB1[256];
    __shared__ __align__(16) float  sB2[144];
    __shared__ __align__(16) float  sEquiQ[192];
    __shared__ float sF[72], sL[72], sL2[72];
    __shared__ int   sAdj[KV];

    if (tid < 256) sB1[tid] = b1[tid] + qc[(size_t)bqid * 256 + tid];
    if (tid < 144) sB2[tid] = (tid < 64) ? b2[72 + tid] : (tid < 136 ? b2[tid - 64] : 0.f);
    if (tid < 192) sEquiQ[tid] = equis[(size_t)bqid * 192 + tid];

    // ---- loop-invariant weights in registers ----
    bf16x8_t w1r[6][2];                 // 32 FF cols per wave, K=192
    #pragma unroll
    for (int ks = 0; ks < 6; ++ks)
        #pragma unroll
        for (int cf = 0; cf < 2; ++cf)
            w1r[ks][cf] = *(const bf16x8_t*)
                &W1bf[((wave << 5) + (cf << 4) + arow) * 192 + ks * 32 + (kgrp << 3)];
    bf16x8_t w2r[8], w2r2[8];           // wave w: tile w; wave 7 also tile 8
    #pragma unroll
    for (int ks = 0; ks < 8; ++ks)
        w2r[ks] = *(const bf16x8_t*)
            &W2bf[(((wave << 4) + arow) << 8) + ks * 32 + (kgrp << 3)];
    if (wave == 7) {
        #pragma unroll
        for (int ks = 0; ks < 8; ++ks)
            w2r2[ks] = *(const bf16x8_t*)
                &W2bf[((128 + arow) << 8) + ks * 32 + (kgrp << 3)];
    }

    // persistent per-thread state
    float m_run = -1e30f, l_run = 0.f, l2_run = 0.f;     // waves 4-7: ch=(wave-4)*16+arow
    float m_rn2 = -1e30f, l_rn2 = 0.f, l2_rn2 = 0.f;     // wave 7, arow<8: ch=64+arow
    float accE = 0.f;                                     // tid<192: (c_e,d_e)
    float accI = 0.f;                                     // tid>=256: fidx
    const int c_e = tid >> 6, d_e = tid & 63;
    const int fidx = tid - 256, h_i = (tid - 256) >> 5;

    __syncthreads();                       // init LDS visible

    for (int kt = 0; kt < 8; ++kt) {
        const int k0 = kt * KV;
        const int kb = b * 256 + k0;

        // ---- phase 1: stage X[kt] (+adj) and passB(kt-1) ----
        #pragma unroll
        for (int gi = 0; gi < 2; ++gi) {
            const int g = (gi == 0) ? tid : 512 + tid;
            if (gi == 1 && tid >= 256) continue;
            const int row = g / 24, c8 = (g % 24) << 3;
            if (c8 < 64) {
                const float* p = &kmsg[(size_t)(kb + row) * 64 + c8];
                *(bf16x8_t*)&sX[swzX(row, c8)] =
                    cvt8(*(const f32x4_t*)p, *(const f32x4_t*)(p + 4));
            } else if (c8 < 128) {
                const int d0 = c8 - 64;
                const float* ek = &equis[(size_t)(kb + row) * 192 + d0];
                f32x4_t e0a = *(const f32x4_t*)(ek),       e0b = *(const f32x4_t*)(ek + 4);
                f32x4_t e1a = *(const f32x4_t*)(ek + 64),  e1b = *(const f32x4_t*)(ek + 68);
                f32x4_t e2a = *(const f32x4_t*)(ek + 128), e2b = *(const f32x4_t*)(ek + 132);
                f32x4_t q0a = *(const f32x4_t*)&sEquiQ[d0],       q0b = *(const f32x4_t*)&sEquiQ[d0 + 4];
                f32x4_t q1a = *(const f32x4_t*)&sEquiQ[64 + d0],  q1b = *(const f32x4_t*)&sEquiQ[68 + d0];
                f32x4_t q2a = *(const f32x4_t*)&sEquiQ[128 + d0], q2b = *(const f32x4_t*)&sEquiQ[132 + d0];
                *(bf16x8_t*)&sX[swzX(row, c8)] =
                    cvt8(e0a * q0a + e1a * q1a + e2a * q2a,
                         e0b * q0b + e1b * q1b + e2b * q2b);
            } else {
                const float* p = &edges[((size_t)bqid * 256 + k0 + row) * 64 + (c8 - 128)];
                *(bf16x8_t*)&sX[swzX(row, c8)] =
                    cvt8(*(const f32x4_t*)p, *(const f32x4_t*)(p + 4));
            }
        }
        if (tid < KV) sAdj[tid] = adj[(size_t)bqid * 256 + k0 + tid];
        if (kt > 0) {
            const int k0P = k0 - KV;
            if (tid < 192) {
                float a = accE * sF[d_e];
                const float* pe = &pTE[(((size_t)b * 3 + c_e) * 64 + d_e) * 256 + k0P];
                #pragma unroll
                for (int t = 0; t < 8; ++t) {
                    f32x4_t w = *(const f32x4_t*)&pe[t * 4];
                    a += sS[(4 * t + 0) * SP + d_e] * w.x;
                    a += sS[(4 * t + 1) * SP + d_e] * w.y;
                    a += sS[(4 * t + 2) * SP + d_e] * w.z;
                    a += sS[(4 * t + 3) * SP + d_e] * w.w;
                }
                accE = a;
            }
            if (tid >= 256) {
                float a = accI * sF[64 + h_i];
                const float* pf = &pTF[((size_t)b * 256 + fidx) * 256 + k0P];
                #pragma unroll
                for (int t = 0; t < 8; ++t) {
                    f32x4_t w = *(const f32x4_t*)&pf[t * 4];
                    a += sS[(4 * t + 0) * SP + 64 + h_i] * w.x;
                    a += sS[(4 * t + 1) * SP + 64 + h_i] * w.y;
                    a += sS[(4 * t + 2) * SP + 64 + h_i] * w.z;
                    a += sS[(4 * t + 3) * SP + 64 + h_i] * w.w;
                }
                accI = a;
            }
        }
        __syncthreads();                   // (A) X staged, passB(kt-1) done

        // ---- phase 2: GEMM1 (K=192, W1 in regs) + silu -> sH ----
        f32x4_t acc1[2][2];
        {
            const f32x4_t z = {0.f, 0.f, 0.f, 0.f};
            acc1[0][0] = z; acc1[0][1] = z; acc1[1][0] = z; acc1[1][1] = z;
        }
        #pragma unroll
        for (int ks = 0; ks < 6; ++ks) {
            const int kk = ks * 32 + (kgrp << 3);
            bf16x8_t a0 = *(const bf16x8_t*)&sX[swzX(arow, kk)];
            bf16x8_t a1 = *(const bf16x8_t*)&sX[swzX(16 + arow, kk)];
            acc1[0][0] = __builtin_amdgcn_mfma_f32_16x16x32_bf16(a0, w1r[ks][0], acc1[0][0], 0, 0, 0);
            acc1[0][1] = __builtin_amdgcn_mfma_f32_16x16x32_bf16(a0, w1r[ks][1], acc1[0][1], 0, 0, 0);
            acc1[1][0] = __builtin_amdgcn_mfma_f32_16x16x32_bf16(a1, w1r[ks][0], acc1[1][0], 0, 0, 0);
            acc1[1][1] = __builtin_amdgcn_mfma_f32_16x16x32_bf16(a1, w1r[ks][1], acc1[1][1], 0, 0, 0);
        }
        #pragma unroll
        for (int rt = 0; rt < 2; ++rt)
            #pragma unroll
            for (int cf = 0; cf < 2; ++cf) {
                const int ccol = (wave << 5) + (cf << 4) + arow;
                const float bb = sB1[ccol];
                #pragma unroll
                for (int j = 0; j < 4; ++j) {
                    const int row = (rt << 4) + (kgrp << 2) + j;
                    float x = acc1[rt][cf][j] + bb;
                    sH[swzH(row, ccol)] = (__bf16)(x / (1.f + __expf(-x)));
                }
            }
        __syncthreads();                   // (B) H ready

        // ---- phase 3: GEMM2 + edge stores + IN-REGISTER softmax -> p ----
        f32x4_t acc2[2], acc2b[2];
        {
            const f32x4_t z = {0.f, 0.f, 0.f, 0.f};
            acc2[0] = z; acc2[1] = z; acc2b[0] = z; acc2b[1] = z;
        }
        #pragma unroll
        for (int ks = 0; ks < 8; ++ks) {
            const int kk = ks * 32 + (kgrp << 3);
            bf16x8_t a0 = *(const bf16x8_t*)&sH[swzH(arow, kk)];
            bf16x8_t a1 = *(const bf16x8_t*)&sH[swzH(16 + arow, kk)];
            acc2[0] = __builtin_amdgcn_mfma_f32_16x16x32_bf16(a0, w2r[ks], acc2[0], 0, 0, 0);
            acc2[1] = __builtin_amdgcn_mfma_f32_16x16x32_bf16(a1, w2r[ks], acc2[1], 0, 0, 0);
            if (wave == 7) {
                acc2b[0] = __builtin_amdgcn_mfma_f32_16x16x32_bf16(a0, w2r2[ks], acc2b[0], 0, 0, 0);
                acc2b[1] = __builtin_amdgcn_mfma_f32_16x16x32_bf16(a1, w2r2[ks], acc2b[1], 0, 0, 0);
            }
        }
        const int col = (wave << 4) + arow;
        if (wave < 4) {
            // edge channels: direct store
            const float bb2 = sB2[col];
            #pragma unroll
            for (int rt = 0; rt < 2; ++rt)
                #pragma unroll
                for (int j = 0; j < 4; ++j) {
                    const int r = (rt << 4) + (kgrp << 2) + j;
                    outEdge[((size_t)bqid * 256 + k0 + r) * 64 + col] = acc2[rt][j] + bb2;
                }
        } else {
            // logit channel ch: this wave holds ALL 32 rows across kgrp lanes
            const int ch = col - 64;
            const float bb2 = sB2[col];
            float s_[8]; int ad_[8];
            float xm = -1e30f;
            #pragma unroll
            for (int rt = 0; rt < 2; ++rt)
                #pragma unroll
                for (int j = 0; j < 4; ++j) {
                    const int r = (rt << 4) + (kgrp << 2) + j;
                    const float v = acc2[rt][j] + bb2;
                    s_[rt * 4 + j] = v;
                    ad_[rt * 4 + j] = sAdj[r];
                    if (ad_[rt * 4 + j]) xm = fmaxf(xm, v);
                }
            xm = fmaxf(xm, __shfl_xor(xm, 16));
            xm = fmaxf(xm, __shfl_xor(xm, 32));
            const float mN = fmaxf(m_run, xm);
            const float f = __expf(m_run - mN);
            float s1 = 0.f, s2 = 0.f;
            #pragma unroll
            for (int rt = 0; rt < 2; ++rt)
                #pragma unroll
                for (int j = 0; j < 4; ++j) {
                    const int r = (rt << 4) + (kgrp << 2) + j;
                    const float p = ad_[rt * 4 + j] ? __expf(s_[rt * 4 + j] - mN) : 0.f;
                    sS[r * SP + ch] = p;
                    s1 += p; s2 += p * p;
                }
            s1 += __shfl_xor(s1, 16); s1 += __shfl_xor(s1, 32);
            s2 += __shfl_xor(s2, 16); s2 += __shfl_xor(s2, 32);
            l_run = l_run * f + s1;
            l2_run = l2_run * f * f + s2;
            m_run = mN;
            if (kgrp == 0) sF[ch] = f;
        }
        if (wave == 7) {
            // tile 8: logit channels 64..71 (lanes arow<8 meaningful)
            const float bb3 = sB2[128 + (arow & 7)];
            float s_[8]; int ad_[8];
            float xm = -1e30f;
            #pragma unroll
            for (int rt = 0; rt < 2; ++rt)
                #pragma unroll
                for (int j = 0; j < 4; ++j) {
                    const int r = (rt << 4) + (kgrp << 2) + j;
                    const float v = acc2b[rt][j] + bb3;
                    s_[rt * 4 + j] = v;
                    ad_[rt * 4 + j] = sAdj[r];
                    if (ad_[rt * 4 + j]) xm = fmaxf(xm, v);
                }
            xm = fmaxf(xm, __shfl_xor(xm, 16));
            xm = fmaxf(xm, __shfl_xor(xm, 32));
            const float mN = fmaxf(m_rn2, xm);
            const float f = __expf(m_rn2 - mN);
            float s1 = 0.f, s2 = 0.f;
            #pragma unroll
            for (int rt = 0; rt < 2; ++rt)
                #pragma unroll
                for (int j = 0; j < 4; ++j) {
                    const int r = (rt << 4) + (kgrp << 2) + j;
                    const float p = ad_[rt * 4 + j] ? __expf(s_[rt * 4 + j] - mN) : 0.f;
                    if (arow < 8) sS[r * SP + 64 + arow] = p;
                    s1 += p; s2 += p * p;
                }
            s1 += __shfl_xor(s1, 16); s1 += __shfl_xor(s1, 32);
            s2 += __shfl_xor(s2, 16); s2 += __shfl_xor(s2, 32);
            l_rn2 = l_rn2 * f + s1;
            l2_rn2 = l2_rn2 * f * f + s2;
            m_rn2 = mN;
            if (kgrp == 0 && arow < 8) sF[64 + arow] = f;
        }
        __syncthreads();                   // (C) p + sF ready
    }

    // ---- final passB (kt=7 tile) ----
    {
        const int k0P = 224;
        if (tid < 192) {
            float a = accE * sF[d_e];
            const float* pe = &pTE[(((size_t)b * 3 + c_e) * 64 + d_e) * 256 + k0P];
            #pragma unroll
            for (int t = 0; t < 8; ++t) {
                f32x4_t w = *(const f32x4_t*)&pe[t * 4];
                a += sS[(4 * t + 0) * SP + d_e] * w.x;
                a += sS[(4 * t + 1) * SP + d_e] * w.y;
                a += sS[(4 * t + 2) * SP + d_e] * w.z;
                a += sS[(4 * t + 3) * SP + d_e] * w.w;
            }
            accE = a;
        }
        if (tid >= 256) {
            float a = accI * sF[64 + h_i];
            const float* pf = &pTF[((size_t)b * 256 + fidx) * 256 + k0P];
            #pragma unroll
            for (int t = 0; t < 8; ++t) {
                f32x4_t w = *(const f32x4_t*)&pf[t * 4];
                a += sS[(4 * t + 0) * SP + 64 + h_i] * w.x;
                a += sS[(4 * t + 1) * SP + 64 + h_i] * w.y;
                a += sS[(4 * t + 2) * SP + 64 + h_i] * w.z;
                a += sS[(4 * t + 3) * SP + 64 + h_i] * w.w;
            }
            accI = a;
        }
    }

    // ---- finalize: publish l, l2; write pre-GEMV outputs ----
    if (wave >= 4 && kgrp == 0) {
        const int ch = ((wave - 4) << 4) + arow;
        sL[ch] = l_run; sL2[ch] = l2_run;
        if (wave == 7 && arow < 8) { sL[64 + arow] = l_rn2; sL2[64 + arow] = l2_rn2; }
    }
    __syncthreads();
    if (tid < 192) {
        const float ll = sL[d_e];
        outE[(size_t)bqid * 192 + tid] = accE * sqrtf(sL2[d_e]) / (ll * ll);
    }
    if (tid >= 256) {
        const float ll = sL[64 + h_i];
        outI[(size_t)bqid * 256 + fidx] = accI * sqrtf(sL2[64 + h_i]) / (ll * ll);
    }
}

// ---------------- post-kernel: final Wa / Wo GEMVs, in place ----------------
__global__ __launch_bounds__(256) void semla_post(
    const float* __restrict__ Wa, const float* __restrict__ Wo,
    const float* __restrict__ bo,
    float* __restrict__ outE, float* __restrict__ outI)
{
    __shared__ __align__(16) float hE[4][192];
    __shared__ __align__(16) float hI[4][256];
    const int blk = blockIdx.x, tid = threadIdx.x;
    const int r0 = blk * 4;
    #pragma unroll
    for (int r = 0; r < 4; ++r) {
        if (tid < 192) hE[r][tid] = outE[(size_t)(r0 + r) * 192 + tid];
        hI[r][tid] = outI[(size_t)(r0 + r) * 256 + tid];
    }
    __syncthreads();
    if (tid < 192) {                        // equi_updates = hE @ Wa^T
        const int c = tid >> 6, e = tid & 63;
        float wa[64];
        #pragma unroll
        for (int d = 0; d < 64; d += 4) {
            f32x4_t w = *(const f32x4_t*)&Wa[e * 64 + d];
            wa[d] = w.x; wa[d + 1] = w.y; wa[d + 2] = w.z; wa[d + 3] = w.w;
        }
        #pragma unroll
        for (int r = 0; r < 4; ++r) {
            float s = 0.f;
            #pragma unroll
            for (int d = 0; d < 64; ++d) s += hE[r][c * 64 + d] * wa[d];
            outE[((size_t)(r0 + r) * 3 + c) * 64 + e] = s;
        }
    }
    {                                       // inv_updates = hI @ Wo^T + bo
        const float bb = bo[tid];
        const float* wo = &Wo[tid * 256];
        #pragma unroll
        for (int r = 0; r < 4; ++r) {
            float s = 0.f;
            for (int i = 0; i < 256; i += 4) {
                f32x4_t w = *(const f32x4_t*)&wo[i];
                s += w.x * hI[r][i] + w.y * hI[r][i + 1]
                   + w.z * hI[r][i + 2] + w.w * hI[r][i + 3];
            }
            outI[(size_t)(r0 + r) * 256 + tid] = s + bb;
        }
    }
}

extern "C" void kernel_launch(void* const* d_in, const int* in_sizes, int n_in,
                              void* d_out, int out_size, void* d_ws, size_t ws_size,
                              hipStream_t stream) {
    (void)in_sizes; (void)n_in; (void)out_size; (void)ws_size;
    const float* equis = (const float*)d_in[0];
    const float* invs  = (const float*)d_in[1];
    const float* edges = (const float*)d_in[2];
    const int*   adj   = (const int*)d_in[3];
    const float* Wq = (const float*)d_in[4];
    const float* bq = (const float*)d_in[5];
    const float* Wk = (const float*)d_in[6];
    const float* bk = (const float*)d_in[7];
    const float* W1 = (const float*)d_in[8];
    const float* b1 = (const float*)d_in[9];
    const float* W2 = (const float*)d_in[10];
    const float* b2 = (const float*)d_in[11];
    const float* Wc = (const float*)d_in[12];
    const float* Wa = (const float*)d_in[13];
    const float* Wi = (const float*)d_in[14];
    const float* bi = (const float*)d_in[15];
    const float* Wo = (const float*)d_in[16];
    const float* bo = (const float*)d_in[17];

    float* out = (float*)d_out;
    float* outE    = out;                  // (B,N,3,64)  = 196608
    float* outI    = out + 196608;         // (B,N,256)   = 262144
    float* outEdge = out + 458752;         // (B,N,N,64)  = 16777216

    char* ws = (char*)d_ws;
    __bf16* W1bf = (__bf16*)(ws);                    //  98304 B (256x192)
    __bf16* W2bf = (__bf16*)(ws + 98304);            //  73728 B (144x256)
    float* qc    = (float*)(ws + 172032);            // 1048576 B
    float* kmsg  = (float*)(ws + 1220608);           //  262144 B
    float* pTE   = (float*)(ws + 1482752);           //  786432 B
    float* pTF   = (float*)(ws + 2269184);           // 1048576 B -> 3317760 total

    semla_pre<<<277, 256, 0, stream>>>(invs, equis, Wq, bq, Wk, bk, Wc, Wi, bi,
                                       W1, W2, W1bf, W2bf, qc, kmsg, pTE, pTF);
    semla_main<<<1024, 512, 0, stream>>>(equis, edges, adj, W1bf, W2bf, qc, kmsg,
                                         pTE, pTF, b1, b2,
                                         outE, outI, outEdge);
    semla_post<<<256, 256, 0, stream>>>(Wa, Wo, bo, outE, outI);
}

// Round 10
// 298.977 us; speedup vs baseline: 3.4331x; 1.0018x over previous
//
#include <hip/hip_runtime.h>
#include <hip/hip_bf16.h>
#include <cstdint>

// SemlaLayer fused forward for MI355X (gfx950).
// R10: 2 barriers/tile. Phase A = edges-prefetch(kt+1) + passB(kt-1) +
// GEMM1+silu; Phase B = staged loads(kt+1) + GEMM2 + in-reg softmax + edge
// stores + X[kt+1] write. Single-buffered sX; sAdj double-buffered.

typedef __bf16 bf16x4_t __attribute__((ext_vector_type(4)));
typedef __bf16 bf16x8_t __attribute__((ext_vector_type(8)));
typedef float  f32x4_t  __attribute__((ext_vector_type(4)));

#define SP 76   // sS pitch in floats
#define KV 32   // k-tile rows

__device__ __forceinline__ int swzX(int row, int col) {   // pitch 192
    return row * 192 + (col ^ ((row & 7) << 3));
}
__device__ __forceinline__ int swzH(int row, int col) {   // pitch 256
    return (row << 8) + (col ^ ((row & 7) << 3));
}

__device__ __forceinline__ bf16x8_t cvt8(f32x4_t a, f32x4_t b) {
    bf16x8_t r;
    r[0] = (__bf16)a.x; r[1] = (__bf16)a.y; r[2] = (__bf16)a.z; r[3] = (__bf16)a.w;
    r[4] = (__bf16)b.x; r[5] = (__bf16)b.y; r[6] = (__bf16)b.z; r[7] = (__bf16)b.w;
    return r;
}
__device__ __forceinline__ bf16x4_t cvt4(f32x4_t a) {
    bf16x4_t r;
    r[0] = (__bf16)a.x; r[1] = (__bf16)a.y; r[2] = (__bf16)a.z; r[3] = (__bf16)a.w;
    return r;
}

// ---------------- pre-kernel ----------------
// blocks 0..255  : 4 (b,n) rows each -> kmsg, pTE, pTF (transposed), qc
// blocks 256..267: W1bf (256x192, W1 cols 64..255)
// blocks 268..276: W2bf (144x256, rows reordered: edge(72..135)|logit(0..71)|pad)
__global__ __launch_bounds__(256) void semla_pre(
    const float* __restrict__ invs, const float* __restrict__ equis,
    const float* __restrict__ Wq, const float* __restrict__ bq,
    const float* __restrict__ Wk, const float* __restrict__ bk,
    const float* __restrict__ Wc, const float* __restrict__ Wi, const float* __restrict__ bi,
    const float* __restrict__ W1, const float* __restrict__ W2,
    __bf16* __restrict__ W1bf, __bf16* __restrict__ W2bf,
    float* __restrict__ qc, float* __restrict__ kmsg,
    float* __restrict__ pTE, float* __restrict__ pTF)
{
    const int blk = blockIdx.x, tid = threadIdx.x;
    if (blk < 256) {
        const int r0 = blk * 4;
        __shared__ __align__(16) float sInv4[4][256];
        __shared__ __align__(16) float sEqu4[4][192];
        __shared__ __align__(16) float sQm4[4][64];
        #pragma unroll
        for (int j = 0; j < 4; ++j) {
            sInv4[j][tid] = invs[(size_t)(r0 + j) * 256 + tid];
            if (tid < 192) sEqu4[j][tid] = equis[(size_t)(r0 + j) * 192 + tid];
        }
        __syncthreads();
        {   // projF = invs @ Wi.T + bi  -> pTF[b][f][n]
            float acc[4] = {0.f, 0.f, 0.f, 0.f};
            const float* w = &Wi[tid * 256];
            for (int i = 0; i < 256; i += 4) {
                f32x4_t ww = *(const f32x4_t*)&w[i];
                #pragma unroll
                for (int j = 0; j < 4; ++j) {
                    const float* x = &sInv4[j][i];
                    acc[j] += ww.x * x[0] + ww.y * x[1] + ww.z * x[2] + ww.w * x[3];
                }
            }
            const float bb = bi[tid];
            #pragma unroll
            for (int j = 0; j < 4; ++j) {
                const int bb_ = (r0 + j) >> 8, nl = (r0 + j) & 255;
                pTF[((size_t)bb_ * 256 + tid) * 256 + nl] = acc[j] + bb;
            }
        }
        if (tid < 128) {   // qmsg (to LDS) / kmsg (to global)
            const int d = tid & 63;
            const float* w = (tid < 64) ? &Wq[d * 256] : &Wk[d * 256];
            float acc[4] = {0.f, 0.f, 0.f, 0.f};
            for (int i = 0; i < 256; i += 4) {
                f32x4_t ww = *(const f32x4_t*)&w[i];
                #pragma unroll
                for (int j = 0; j < 4; ++j) {
                    const float* x = &sInv4[j][i];
                    acc[j] += ww.x * x[0] + ww.y * x[1] + ww.z * x[2] + ww.w * x[3];
                }
            }
            if (tid < 64) {
                const float bb = bq[d];
                #pragma unroll
                for (int j = 0; j < 4; ++j) sQm4[j][d] = acc[j] + bb;
            } else {
                const float bb = bk[d];
                #pragma unroll
                for (int j = 0; j < 4; ++j) kmsg[(size_t)(r0 + j) * 64 + d] = acc[j] + bb;
            }
        }
        if (tid < 192) {   // projE = equis @ Wc.T -> pTE[b][c][d][n]
            const int c = tid >> 6, e = tid & 63;
            const float* w = &Wc[e * 64];
            float acc[4] = {0.f, 0.f, 0.f, 0.f};
            for (int dd = 0; dd < 64; dd += 4) {
                f32x4_t ww = *(const f32x4_t*)&w[dd];
                #pragma unroll
                for (int j = 0; j < 4; ++j) {
                    const float* x = &sEqu4[j][c * 64 + dd];
                    acc[j] += ww.x * x[0] + ww.y * x[1] + ww.z * x[2] + ww.w * x[3];
                }
            }
            #pragma unroll
            for (int j = 0; j < 4; ++j) {
                const int bb_ = (r0 + j) >> 8, nl = (r0 + j) & 255;
                pTE[(((size_t)bb_ * 3 + c) * 64 + e) * 256 + nl] = acc[j];
            }
        }
        __syncthreads();   // sQm4 ready
        {   // qc[r][o] = sum_{d<64} W1[o][d] * qmsg[r][d]
            const float* w = &W1[tid * 256];
            float acc[4] = {0.f, 0.f, 0.f, 0.f};
            for (int d = 0; d < 64; d += 4) {
                f32x4_t ww = *(const f32x4_t*)&w[d];
                #pragma unroll
                for (int j = 0; j < 4; ++j) {
                    const float* x = &sQm4[j][d];
                    acc[j] += ww.x * x[0] + ww.y * x[1] + ww.z * x[2] + ww.w * x[3];
                }
            }
            #pragma unroll
            for (int j = 0; j < 4; ++j) qc[(size_t)(r0 + j) * 256 + tid] = acc[j];
        }
    } else if (blk < 268) {   // W1bf: 256x192, source col 64+k
        const int base = (blk - 256) * 4096;
        #pragma unroll
        for (int it = 0; it < 16; ++it) {
            const int e = base + it * 256 + tid;   // < 49152
            const int o = e / 192, k = e % 192;
            W1bf[e] = (__bf16)W1[o * 256 + 64 + k];
        }
    } else if (blk < 277) {   // W2bf reordered
        const int base = (blk - 268) * 4096;
        #pragma unroll
        for (int it = 0; it < 16; ++it) {
            const int e = base + it * 256 + tid;   // < 36864
            const int o = e >> 8, cc = e & 255;
            const int src = (o < 64) ? (72 + o) : (o < 136 ? o - 64 : -1);
            W2bf[e] = (src >= 0) ? (__bf16)W2[src * 256 + cc] : (__bf16)0.f;
        }
    }
}

// ---------------- main fused kernel: one 8-wave workgroup per (b,q) ---------
__global__ __launch_bounds__(512, 2) void semla_main(
    const float* __restrict__ equis, const float* __restrict__ edges,
    const int* __restrict__ adj,
    const __bf16* __restrict__ W1bf, const __bf16* __restrict__ W2bf,
    const float* __restrict__ qc, const float* __restrict__ kmsg,
    const float* __restrict__ pTE, const float* __restrict__ pTF,
    const float* __restrict__ b1, const float* __restrict__ b2,
    float* __restrict__ outE, float* __restrict__ outI, float* __restrict__ outEdge)
{
    const int bqid = ((blockIdx.x & 7) << 7) | (blockIdx.x >> 3);  // XCD swizzle
    const int b = bqid >> 8;
    const int tid = threadIdx.x;
    const int wave = tid >> 6, lane = tid & 63;
    const int arow = lane & 15, kgrp = lane >> 4;

    __shared__ __align__(16) __bf16 sX[KV * 192];   // 12KB X tile (K=192)
    __shared__ __align__(16) __bf16 sH[KV * 256];   // 16KB H tile
    __shared__ __align__(16) float  sS[KV * SP];    // p values
    __shared__ __align__(16) float  sB1[256];
    __shared__ __align__(16) float  sB2[144];
    __shared__ __align__(16) float  sEquiQ[192];
    __shared__ float sF[72], sL[72], sL2[72];
    __shared__ int   sAdj[2][KV];

    if (tid < 256) sB1[tid] = b1[tid] + qc[(size_t)bqid * 256 + tid];
    if (tid < 144) sB2[tid] = (tid < 64) ? b2[72 + tid] : (tid < 136 ? b2[tid - 64] : 0.f);
    if (tid < 192) sEquiQ[tid] = equis[(size_t)bqid * 192 + tid];

    // ---- loop-invariant weights in registers ----
    bf16x8_t w1r[6][2];                 // 32 FF cols per wave, K=192
    #pragma unroll
    for (int ks = 0; ks < 6; ++ks)
        #pragma unroll
        for (int cf = 0; cf < 2; ++cf)
            w1r[ks][cf] = *(const bf16x8_t*)
                &W1bf[((wave << 5) + (cf << 4) + arow) * 192 + ks * 32 + (kgrp << 3)];
    bf16x8_t w2r[8], w2r2[8];           // wave w: tile w; wave 7 also tile 8
    #pragma unroll
    for (int ks = 0; ks < 8; ++ks)
        w2r[ks] = *(const bf16x8_t*)
            &W2bf[(((wave << 4) + arow) << 8) + ks * 32 + (kgrp << 3)];
    if (wave == 7) {
        #pragma unroll
        for (int ks = 0; ks < 8; ++ks)
            w2r2[ks] = *(const bf16x8_t*)
                &W2bf[((128 + arow) << 8) + ks * 32 + (kgrp << 3)];
    }

    // persistent per-thread state
    float m_run = -1e30f, l_run = 0.f, l2_run = 0.f;     // waves 4-7: ch=(wave-4)*16+arow
    float m_rn2 = -1e30f, l_rn2 = 0.f, l2_rn2 = 0.f;     // wave 7, arow<8: ch=64+arow
    float accE = 0.f;                                     // tid<192: (c_e,d_e)
    float accI = 0.f;                                     // tid>=256: fidx
    const int c_e = tid >> 6, d_e = tid & 63;
    const int fidx = tid - 256, h_i = (tid - 256) >> 5;

    // staging roles (valid for both halves): row = (tid&255)>>3, colbase = (tid&7)<<3
    const int rowS = (tid & 255) >> 3;
    const int c8S = (tid & 7) << 3;
    const int pchunk = tid >> 1, prow = pchunk >> 3;
    const int pcol = 128 + ((pchunk & 7) << 3) + ((tid & 1) << 2);   // edges col in X

    __syncthreads();                       // init LDS (sEquiQ, sB1) visible

    // ---- prologue: stage X[0] + sAdj[0] ----
    {
        if (tid < 256) {
            const float* p = &kmsg[(size_t)(b * 256 + rowS) * 64 + c8S];
            *(bf16x8_t*)&sX[swzX(rowS, c8S)] =
                cvt8(*(const f32x4_t*)p, *(const f32x4_t*)(p + 4));
        } else {
            const float* ek = &equis[(size_t)(b * 256 + rowS) * 192 + c8S];
            f32x4_t e0a = *(const f32x4_t*)(ek),       e0b = *(const f32x4_t*)(ek + 4);
            f32x4_t e1a = *(const f32x4_t*)(ek + 64),  e1b = *(const f32x4_t*)(ek + 68);
            f32x4_t e2a = *(const f32x4_t*)(ek + 128), e2b = *(const f32x4_t*)(ek + 132);
            f32x4_t q0a = *(const f32x4_t*)&sEquiQ[c8S],       q0b = *(const f32x4_t*)&sEquiQ[c8S + 4];
            f32x4_t q1a = *(const f32x4_t*)&sEquiQ[64 + c8S],  q1b = *(const f32x4_t*)&sEquiQ[68 + c8S];
            f32x4_t q2a = *(const f32x4_t*)&sEquiQ[128 + c8S], q2b = *(const f32x4_t*)&sEquiQ[132 + c8S];
            *(bf16x8_t*)&sX[swzX(rowS, 64 + c8S)] =
                cvt8(e0a * q0a + e1a * q1a + e2a * q2a,
                     e0b * q0b + e1b * q1b + e2b * q2b);
        }
        f32x4_t ed = *(const f32x4_t*)&edges[((size_t)bqid * 256 + prow) * 64 + (pcol - 128)];
        *(bf16x4_t*)&sX[swzX(prow, pcol)] = cvt4(ed);
        if (tid < KV) sAdj[0][tid] = adj[(size_t)bqid * 256 + tid];
    }
    __syncthreads();                       // X[0] ready

    for (int kt = 0; kt < 8; ++kt) {
        const int k0 = kt * KV;
        const int cur = kt & 1;

        // ============ PHASE A: prefetch + passB(kt-1) + GEMM1 + silu ============
        f32x4_t edPf = {0.f, 0.f, 0.f, 0.f};
        if (kt < 7)
            edPf = *(const f32x4_t*)
                &edges[((size_t)bqid * 256 + k0 + KV + prow) * 64 + (pcol - 128)];

        if (kt > 0) {
            const int k0P = k0 - KV;
            if (tid < 192) {
                float a = accE * sF[d_e];
                const float* pe = &pTE[(((size_t)b * 3 + c_e) * 64 + d_e) * 256 + k0P];
                #pragma unroll
                for (int t = 0; t < 8; ++t) {
                    f32x4_t w = *(const f32x4_t*)&pe[t * 4];
                    a += sS[(4 * t + 0) * SP + d_e] * w.x;
                    a += sS[(4 * t + 1) * SP + d_e] * w.y;
                    a += sS[(4 * t + 2) * SP + d_e] * w.z;
                    a += sS[(4 * t + 3) * SP + d_e] * w.w;
                }
                accE = a;
            }
            if (tid >= 256) {
                float a = accI * sF[64 + h_i];
                const float* pf = &pTF[((size_t)b * 256 + fidx) * 256 + k0P];
                #pragma unroll
                for (int t = 0; t < 8; ++t) {
                    f32x4_t w = *(const f32x4_t*)&pf[t * 4];
                    a += sS[(4 * t + 0) * SP + 64 + h_i] * w.x;
                    a += sS[(4 * t + 1) * SP + 64 + h_i] * w.y;
                    a += sS[(4 * t + 2) * SP + 64 + h_i] * w.z;
                    a += sS[(4 * t + 3) * SP + 64 + h_i] * w.w;
                }
                accI = a;
            }
        }

        // GEMM1 (K=192, W1 in regs) + silu -> sH
        f32x4_t acc1[2][2];
        {
            const f32x4_t z = {0.f, 0.f, 0.f, 0.f};
            acc1[0][0] = z; acc1[0][1] = z; acc1[1][0] = z; acc1[1][1] = z;
        }
        #pragma unroll
        for (int ks = 0; ks < 6; ++ks) {
            const int kk = ks * 32 + (kgrp << 3);
            bf16x8_t a0 = *(const bf16x8_t*)&sX[swzX(arow, kk)];
            bf16x8_t a1 = *(const bf16x8_t*)&sX[swzX(16 + arow, kk)];
            acc1[0][0] = __builtin_amdgcn_mfma_f32_16x16x32_bf16(a0, w1r[ks][0], acc1[0][0], 0, 0, 0);
            acc1[0][1] = __builtin_amdgcn_mfma_f32_16x16x32_bf16(a0, w1r[ks][1], acc1[0][1], 0, 0, 0);
            acc1[1][0] = __builtin_amdgcn_mfma_f32_16x16x32_bf16(a1, w1r[ks][0], acc1[1][0], 0, 0, 0);
            acc1[1][1] = __builtin_amdgcn_mfma_f32_16x16x32_bf16(a1, w1r[ks][1], acc1[1][1], 0, 0, 0);
        }
        #pragma unroll
        for (int rt = 0; rt < 2; ++rt)
            #pragma unroll
            for (int cf = 0; cf < 2; ++cf) {
                const int ccol = (wave << 5) + (cf << 4) + arow;
                const float bb = sB1[ccol];
                #pragma unroll
                for (int j = 0; j < 4; ++j) {
                    const int row = (rt << 4) + (kgrp << 2) + j;
                    float x = acc1[rt][cf][j] + bb;
                    sH[swzH(row, ccol)] = (__bf16)(x / (1.f + __expf(-x)));
                }
            }
        __syncthreads();                   // (1) H ready, passB done, sS free

        // ============ PHASE B: staged loads + GEMM2 + softmax + X[kt+1] ============
        f32x4_t kmA, kmB;                                   // tid<256
        f32x4_t e0a_, e0b_, e1a_, e1b_, e2a_, e2b_;         // tid>=256
        int adjN = 0;
        if (kt < 7) {
            const int kbN = b * 256 + k0 + KV;
            if (tid < 256) {
                const float* p = &kmsg[(size_t)(kbN + rowS) * 64 + c8S];
                kmA = *(const f32x4_t*)p;
                kmB = *(const f32x4_t*)(p + 4);
            } else {
                const float* ek = &equis[(size_t)(kbN + rowS) * 192 + c8S];
                e0a_ = *(const f32x4_t*)(ek);       e0b_ = *(const f32x4_t*)(ek + 4);
                e1a_ = *(const f32x4_t*)(ek + 64);  e1b_ = *(const f32x4_t*)(ek + 68);
                e2a_ = *(const f32x4_t*)(ek + 128); e2b_ = *(const f32x4_t*)(ek + 132);
            }
            if (tid < KV) adjN = adj[(size_t)bqid * 256 + k0 + KV + tid];
        }

        // GEMM2 (W2 in regs)
        f32x4_t acc2[2], acc2b[2];
        {
            const f32x4_t z = {0.f, 0.f, 0.f, 0.f};
            acc2[0] = z; acc2[1] = z; acc2b[0] = z; acc2b[1] = z;
        }
        #pragma unroll
        for (int ks = 0; ks < 8; ++ks) {
            const int kk = ks * 32 + (kgrp << 3);
            bf16x8_t a0 = *(const bf16x8_t*)&sH[swzH(arow, kk)];
            bf16x8_t a1 = *(const bf16x8_t*)&sH[swzH(16 + arow, kk)];
            acc2[0] = __builtin_amdgcn_mfma_f32_16x16x32_bf16(a0, w2r[ks], acc2[0], 0, 0, 0);
            acc2[1] = __builtin_amdgcn_mfma_f32_16x16x32_bf16(a1, w2r[ks], acc2[1], 0, 0, 0);
            if (wave == 7) {
                acc2b[0] = __builtin_amdgcn_mfma_f32_16x16x32_bf16(a0, w2r2[ks], acc2b[0], 0, 0, 0);
                acc2b[1] = __builtin_amdgcn_mfma_f32_16x16x32_bf16(a1, w2r2[ks], acc2b[1], 0, 0, 0);
            }
        }
        const int col = (wave << 4) + arow;
        if (wave < 4) {
            // edge channels: direct store
            const float bb2 = sB2[col];
            #pragma unroll
            for (int rt = 0; rt < 2; ++rt)
                #pragma unroll
                for (int j = 0; j < 4; ++j) {
                    const int r = (rt << 4) + (kgrp << 2) + j;
                    outEdge[((size_t)bqid * 256 + k0 + r) * 64 + col] = acc2[rt][j] + bb2;
                }
        } else {
            // logit channel ch: wave holds all 32 rows across kgrp lanes
            const int ch = col - 64;
            const float bb2 = sB2[col];
            float s_[8]; int ad_[8];
            float xm = -1e30f;
            #pragma unroll
            for (int rt = 0; rt < 2; ++rt)
                #pragma unroll
                for (int j = 0; j < 4; ++j) {
                    const int r = (rt << 4) + (kgrp << 2) + j;
                    const float v = acc2[rt][j] + bb2;
                    s_[rt * 4 + j] = v;
                    ad_[rt * 4 + j] = sAdj[cur][r];
                    if (ad_[rt * 4 + j]) xm = fmaxf(xm, v);
                }
            xm = fmaxf(xm, __shfl_xor(xm, 16));
            xm = fmaxf(xm, __shfl_xor(xm, 32));
            const float mN = fmaxf(m_run, xm);
            const float f = __expf(m_run - mN);
            float s1 = 0.f, s2 = 0.f;
            #pragma unroll
            for (int rt = 0; rt < 2; ++rt)
                #pragma unroll
                for (int j = 0; j < 4; ++j) {
                    const int r = (rt << 4) + (kgrp << 2) + j;
                    const float p = ad_[rt * 4 + j] ? __expf(s_[rt * 4 + j] - mN) : 0.f;
                    sS[r * SP + ch] = p;
                    s1 += p; s2 += p * p;
                }
            s1 += __shfl_xor(s1, 16); s1 += __shfl_xor(s1, 32);
            s2 += __shfl_xor(s2, 16); s2 += __shfl_xor(s2, 32);
            l_run = l_run * f + s1;
            l2_run = l2_run * f * f + s2;
            m_run = mN;
            if (kgrp == 0) sF[ch] = f;
        }
        if (wave == 7) {
            // tile 8: logit channels 64..71 (lanes arow<8 meaningful)
            const float bb3 = sB2[128 + (arow & 7)];
            float s_[8]; int ad_[8];
            float xm = -1e30f;
            #pragma unroll
            for (int rt = 0; rt < 2; ++rt)
                #pragma unroll
                for (int j = 0; j < 4; ++j) {
                    const int r = (rt << 4) + (kgrp << 2) + j;
                    const float v = acc2b[rt][j] + bb3;
                    s_[rt * 4 + j] = v;
                    ad_[rt * 4 + j] = sAdj[cur][r];
                    if (ad_[rt * 4 + j]) xm = fmaxf(xm, v);
                }
            xm = fmaxf(xm, __shfl_xor(xm, 16));
            xm = fmaxf(xm, __shfl_xor(xm, 32));
            const float mN = fmaxf(m_rn2, xm);
            const float f = __expf(m_rn2 - mN);
            float s1 = 0.f, s2 = 0.f;
            #pragma unroll
            for (int rt = 0; rt < 2; ++rt)
                #pragma unroll
                for (int j = 0; j < 4; ++j) {
                    const int r = (rt << 4) + (kgrp << 2) + j;
                    const float p = ad_[rt * 4 + j] ? __expf(s_[rt * 4 + j] - mN) : 0.f;
                    if (arow < 8) sS[r * SP + 64 + arow] = p;
                    s1 += p; s2 += p * p;
                }
            s1 += __shfl_xor(s1, 16); s1 += __shfl_xor(s1, 32);
            s2 += __shfl_xor(s2, 16); s2 += __shfl_xor(s2, 32);
            l_rn2 = l_rn2 * f + s1;
            l2_rn2 = l2_rn2 * f * f + s2;
            m_rn2 = mN;
            if (kgrp == 0 && arow < 8) sF[64 + arow] = f;
        }

        // write X[kt+1] from staged regs (sX free since barrier (1))
        if (kt < 7) {
            if (tid < 256) {
                *(bf16x8_t*)&sX[swzX(rowS, c8S)] = cvt8(kmA, kmB);
            } else {
                f32x4_t q0a = *(const f32x4_t*)&sEquiQ[c8S],       q0b = *(const f32x4_t*)&sEquiQ[c8S + 4];
                f32x4_t q1a = *(const f32x4_t*)&sEquiQ[64 + c8S],  q1b = *(const f32x4_t*)&sEquiQ[68 + c8S];
                f32x4_t q2a = *(const f32x4_t*)&sEquiQ[128 + c8S], q2b = *(const f32x4_t*)&sEquiQ[132 + c8S];
                *(bf16x8_t*)&sX[swzX(rowS, 64 + c8S)] =
                    cvt8(e0a_ * q0a + e1a_ * q1a + e2a_ * q2a,
                         e0b_ * q0b + e1b_ * q1b + e2b_ * q2b);
            }
            *(bf16x4_t*)&sX[swzX(prow, pcol)] = cvt4(edPf);
            if (tid < KV) sAdj[cur ^ 1][tid] = adjN;
        }
        __syncthreads();                   // (2) sS/sF + X[kt+1] ready
    }

    // ---- final passB (kt=7 tile) ----
    {
        const int k0P = 224;
        if (tid < 192) {
            float a = accE * sF[d_e];
            const float* pe = &pTE[(((size_t)b * 3 + c_e) * 64 + d_e) * 256 + k0P];
            #pragma unroll
            for (int t = 0; t < 8; ++t) {
                f32x4_t w = *(const f32x4_t*)&pe[t * 4];
                a += sS[(4 * t + 0) * SP + d_e] * w.x;
                a += sS[(4 * t + 1) * SP + d_e] * w.y;
                a += sS[(4 * t + 2) * SP + d_e] * w.z;
                a += sS[(4 * t + 3) * SP + d_e] * w.w;
            }
            accE = a;
        }
        if (tid >= 256) {
            float a = accI * sF[64 + h_i];
            const float* pf = &pTF[((size_t)b * 256 + fidx) * 256 + k0P];
            #pragma unroll
            for (int t = 0; t < 8; ++t) {
                f32x4_t w = *(const f32x4_t*)&pf[t * 4];
                a += sS[(4 * t + 0) * SP + 64 + h_i] * w.x;
                a += sS[(4 * t + 1) * SP + 64 + h_i] * w.y;
                a += sS[(4 * t + 2) * SP + 64 + h_i] * w.z;
                a += sS[(4 * t + 3) * SP + 64 + h_i] * w.w;
            }
            accI = a;
        }
    }

    // ---- finalize: publish l, l2; write pre-GEMV outputs ----
    if (wave >= 4 && kgrp == 0) {
        const int ch = ((wave - 4) << 4) + arow;
        sL[ch] = l_run; sL2[ch] = l2_run;
        if (wave == 7 && arow < 8) { sL[64 + arow] = l_rn2; sL2[64 + arow] = l2_rn2; }
    }
    __syncthreads();
    if (tid < 192) {
        const float ll = sL[d_e];
        outE[(size_t)bqid * 192 + tid] = accE * sqrtf(sL2[d_e]) / (ll * ll);
    }
    if (tid >= 256) {
        const float ll = sL[64 + h_i];
        outI[(size_t)bqid * 256 + fidx] = accI * sqrtf(sL2[64 + h_i]) / (ll * ll);
    }
}

// ---------------- post-kernel: final Wa / Wo GEMVs, in place ----------------
__global__ __launch_bounds__(256) void semla_post(
    const float* __restrict__ Wa, const float* __restrict__ Wo,
    const float* __restrict__ bo,
    float* __restrict__ outE, float* __restrict__ outI)
{
    __shared__ __align__(16) float hE[4][192];
    __shared__ __align__(16) float hI[4][256];
    const int blk = blockIdx.x, tid = threadIdx.x;
    const int r0 = blk * 4;
    #pragma unroll
    for (int r = 0; r < 4; ++r) {
        if (tid < 192) hE[r][tid] = outE[(size_t)(r0 + r) * 192 + tid];
        hI[r][tid] = outI[(size_t)(r0 + r) * 256 + tid];
    }
    __syncthreads();
    if (tid < 192) {                        // equi_updates = hE @ Wa^T
        const int c = tid >> 6, e = tid & 63;
        float wa[64];
        #pragma unroll
        for (int d = 0; d < 64; d += 4) {
            f32x4_t w = *(const f32x4_t*)&Wa[e * 64 + d];
            wa[d] = w.x; wa[d + 1] = w.y; wa[d + 2] = w.z; wa[d + 3] = w.w;
        }
        #pragma unroll
        for (int r = 0; r < 4; ++r) {
            float s = 0.f;
            #pragma unroll
            for (int d = 0; d < 64; ++d) s += hE[r][c * 64 + d] * wa[d];
            outE[((size_t)(r0 + r) * 3 + c) * 64 + e] = s;
        }
    }
    {                                       // inv_updates = hI @ Wo^T + bo
        const float bb = bo[tid];
        const float* wo = &Wo[tid * 256];
        #pragma unroll
        for (int r = 0; r < 4; ++r) {
            float s = 0.f;
            for (int i = 0; i < 256; i += 4) {
                f32x4_t w = *(const f32x4_t*)&wo[i];
                s += w.x * hI[r][i] + w.y * hI[r][i + 1]
                   + w.z * hI[r][i + 2] + w.w * hI[r][i + 3];
            }
            outI[(size_t)(r0 + r) * 256 + tid] = s + bb;
        }
    }
}

extern "C" void kernel_launch(void* const* d_in, const int* in_sizes, int n_in,
                              void* d_out, int out_size, void* d_ws, size_t ws_size,
                              hipStream_t stream) {
    (void)in_sizes; (void)n_in; (void)out_size; (void)ws_size;
    const float* equis = (const float*)d_in[0];
    const float* invs  = (const float*)d_in[1];
    const float* edges = (const float*)d_in[2];
    const int*   adj   = (const int*)d_in[3];
    const float* Wq = (const float*)d_in[4];
    const float* bq = (const float*)d_in[5];
    const float* Wk = (const float*)d_in[6];
    const float* bk = (const float*)d_in[7];
    const float* W1 = (const float*)d_in[8];
    const float* b1 = (const float*)d_in[9];
    const float* W2 = (const float*)d_in[10];
    const float* b2 = (const float*)d_in[11];
    const float* Wc = (const float*)d_in[12];
    const float* Wa = (const float*)d_in[13];
    const float* Wi = (const float*)d_in[14];
    const float* bi = (const float*)d_in[15];
    const float* Wo = (const float*)d_in[16];
    const float* bo = (const float*)d_in[17];

    float* out = (float*)d_out;
    float* outE    = out;                  // (B,N,3,64)  = 196608
    float* outI    = out + 196608;         // (B,N,256)   = 262144
    float* outEdge = out + 458752;         // (B,N,N,64)  = 16777216

    char* ws = (char*)d_ws;
    __bf16* W1bf = (__bf16*)(ws);                    //  98304 B (256x192)
    __bf16* W2bf = (__bf16*)(ws + 98304);            //  73728 B (144x256)
    float* qc    = (float*)(ws + 172032);            // 1048576 B
    float* kmsg  = (float*)(ws + 1220608);           //  262144 B
    float* pTE   = (float*)(ws + 1482752);           //  786432 B
    float* pTF   = (float*)(ws + 2269184);           // 1048576 B -> 3317760 total

    semla_pre<<<277, 256, 0, stream>>>(invs, equis, Wq, bq, Wk, bk, Wc, Wi, bi,
                                       W1, W2, W1bf, W2bf, qc, kmsg, pTE, pTF);
    semla_main<<<1024, 512, 0, stream>>>(equis, edges, adj, W1bf, W2bf, qc, kmsg,
                                         pTE, pTF, b1, b2,
                                         outE, outI, outEdge);
    semla_post<<<256, 256, 0, stream>>>(Wa, Wo, bo, outE, outI);
}